// Round 5
// baseline (868.911 us; speedup 1.0000x reference)
//
#include <hip/hip_runtime.h>
#include <cstddef>
#include <cstdint>
#include <math.h>

#define B_   1024
#define L_   18
#define E_   300
#define H_   300
#define M_   (B_*L_)     // 18432 rows (b,l)
#define G4_  (4*H_)      // 1200
#define K2E_ (2*E_)      // 600

#define NPAD 2432        // gate-interleaved cols, both dirs (2*1216)
#define PSTR 2432        // P1/P2 row stride (fp32)
#define M2P  2304        // P2 padded rows (2186 valid)

// workspace layout (float offsets)
#define OFF_P1   ((size_t)0)                         // fp32 1024x2432
#define OFF_P2   (OFF_P1 + (size_t)1024*PSTR)        // fp32 2304x2432 (+bias)
#define OFF_HCAT (OFF_P2 + (size_t)M2P*PSTR)         // bf16 18432x608
#define OFF_AG   (OFF_HCAT + (size_t)M_*608/2)
#define OFF_WBT  (OFF_AG  + (size_t)B_*E_)
#define OFF_WFF  (OFF_WBT + 90000)                   // bf16 76x10x512 B-frag
#define OFF_WFB  (OFF_WFF + 194560)
#define OFF_WAT  (OFF_WFB + 194560)                  // bf16 19x19x512 B-frag
#define OFF_WCP  (OFF_WAT + 92416)                   // bf16 2x2432x320

#define VOFF ((size_t)M_*H_)  // v_g offset in d_out

typedef short bf16x8 __attribute__((ext_vector_type(8)));
typedef float f32x4  __attribute__((ext_vector_type(4)));

__device__ __forceinline__ short f2bf(float f) {
    union { float f; uint32_t u; } c; c.f = f;
    uint32_t u = c.u + 0x7fffu + ((c.u >> 16) & 1u);   // RNE
    return (short)(u >> 16);
}

// ---------------------------------------------------------------------------
// WbT[k][o] = Wb[o*300 + k]
// ---------------------------------------------------------------------------
__global__ void k_prep(const float* __restrict__ Wb, float* __restrict__ WbT)
{
    int idx = blockIdx.x * 256 + threadIdx.x;
    if (idx < 90000) {
        int o = idx % 300;
        int k = idx / 300;
        WbT[idx] = Wb[o * 300 + k];
    }
}

// ---------------------------------------------------------------------------
// WcatP[p][n'][kp] bf16: p=0 -> Wih[:, kp], p=1 -> Wih[:, 300+kp].
// n' gate-interleaved: n'<1216 fwd (n'=4u+g -> row g*300+u), else bwd.
// ---------------------------------------------------------------------------
__global__ __launch_bounds__(256) void k_prep_wcp(const float* __restrict__ Wih_f,
                                                  const float* __restrict__ Wih_b,
                                                  short* __restrict__ WcatP)
{
    int idx = blockIdx.x * 256 + threadIdx.x;   // < 2*2432*320
    if (idx >= 2 * NPAD * 320) return;
    int p = idx / (NPAD * 320);
    int rem = idx - p * (NPAD * 320);
    int n = rem / 320;
    int kp = rem - n * 320;
    int fwd = (n < 1216);
    int nn = fwd ? n : n - 1216;
    float v = 0.f;
    if (kp < 300 && nn < G4_) {
        int u = nn >> 2, g = nn & 3;
        const float* W = fwd ? Wih_f : Wih_b;
        v = W[(size_t)(g * 300 + u) * K2E_ + (p ? 300 + kp : kp)];
    }
    WcatP[idx] = f2bf(v);
}

// ---------------------------------------------------------------------------
// Whh B-fragment pack: WF[d][(nt*10+kt)*512 + lane*8 + j] =
//   bf16(Whh_d[(g*300+u)*300 + k]),  n = nt*16+(lane&15) = 4u+g,
//   k = kt*32 + (lane>>4)*8 + j; zero pads.
// ---------------------------------------------------------------------------
__global__ __launch_bounds__(256) void k_prep_whh(const float* __restrict__ Whh_f,
                                                  const float* __restrict__ Whh_b,
                                                  short* __restrict__ WFf,
                                                  short* __restrict__ WFb)
{
    int idx = blockIdx.x * 256 + threadIdx.x;   // < 389120
    if (idx >= 389120) return;
    int d = blockIdx.y;
    int chunk = idx >> 9;           // nt*10+kt
    int rem   = idx & 511;
    int lane  = rem >> 3;
    int j     = rem & 7;
    int nt = chunk / 10, kt = chunk - nt * 10;
    int n = nt * 16 + (lane & 15);
    int k = kt * 32 + (lane >> 4) * 8 + j;
    float v = 0.f;
    if (n < G4_ && k < H_) {
        int u = n >> 2, g = n & 3;
        const float* W = d ? Whh_b : Whh_f;
        v = W[(size_t)(g * 300 + u) * H_ + k];
    }
    (d ? WFb : WFf)[idx] = f2bf(v);
}

// ---------------------------------------------------------------------------
// Wa B-fragment pack for k_out: N=304 (19 nt), K=608 (19 kt).
// ---------------------------------------------------------------------------
__global__ __launch_bounds__(256) void k_prep_wa(const float* __restrict__ Wa,
                                                 short* __restrict__ WAT)
{
    int idx = blockIdx.x * 256 + threadIdx.x;   // < 184832
    if (idx >= 184832) return;
    int chunk = idx >> 9;           // nt*19+kt
    int rem   = idx & 511;
    int lane  = rem >> 3;
    int j     = rem & 7;
    int nt = chunk / 19, kt = chunk - nt * 19;
    int o  = nt * 16 + (lane & 15);
    int kp = kt * 32 + (lane >> 4) * 8 + j;
    float v = 0.f;
    if (o < H_) {
        int k = -1;
        if (kp < 300)                   k = kp;
        else if (kp >= 304 && kp < 604) k = kp - 4;
        if (k >= 0) v = Wa[(size_t)o * K2E_ + k];
    }
    WAT[idx] = f2bf(v);
}

// ---------------------------------------------------------------------------
// a_g[b][e] = mean_l sem_table[sememes[b][l]][e]
// ---------------------------------------------------------------------------
__global__ __launch_bounds__(256) void k_ag(const int* __restrict__ sem,
                                            const float* __restrict__ sem_table,
                                            float* __restrict__ ag)
{
    int b = blockIdx.x;
    __shared__ int sm[L_];
    if (threadIdx.x < L_) sm[threadIdx.x] = sem[b * L_ + threadIdx.x];
    __syncthreads();
    for (int e = threadIdx.x; e < E_; e += 256) {
        float s = 0.f;
        #pragma unroll
        for (int l = 0; l < L_; ++l) s += sem_table[sm[l] * E_ + e];
        ag[(size_t)b * E_ + e] = s * (1.0f / (float)L_);
    }
}

// ---------------------------------------------------------------------------
// v_g = relu(a_g @ Wb^T + bb) -> d_out[VOFF + ...]
// ---------------------------------------------------------------------------
__global__ __launch_bounds__(256) void k_vg(const float* __restrict__ ag,
                                            const float* __restrict__ WbT,
                                            const float* __restrict__ bbv,
                                            float* __restrict__ out)
{
    int b0 = blockIdx.x * 16;
    __shared__ __align__(16) float ag_s[16 * E_];
    for (int idx = threadIdx.x; idx < 16 * E_; idx += 256)
        ag_s[idx] = ag[(size_t)b0 * E_ + idx];
    __syncthreads();
    for (int o = threadIdx.x; o < E_; o += 256) {
        float acc[16];
        #pragma unroll
        for (int i = 0; i < 16; ++i) acc[i] = 0.f;
        for (int k = 0; k < E_; ++k) {
            float w = WbT[k * E_ + o];
            #pragma unroll
            for (int i = 0; i < 16; ++i)
                acc[i] = fmaf(w, ag_s[i * E_ + k], acc[i]);
        }
        float bias = bbv[o];
        #pragma unroll
        for (int i = 0; i < 16; ++i) {
            float v = acc[i] + bias;
            out[VOFF + (size_t)(b0 + i) * E_ + o] = v > 0.f ? v : 0.f;
        }
    }
}

// ---------------------------------------------------------------------------
// k_p: P1 = w @ Wih1^T  (rows 0..1023, mb 0..7)
//      P2' = sem_table @ Wih2^T + bias  (rows 0..2303, mb 8..25)
// bf16 MFMA, 128x128 tiles, K=320 (300 valid). Grid (26, 19).
// ---------------------------------------------------------------------------
#define LDT 40

__global__ __launch_bounds__(256) void k_p(const int* __restrict__ word,
                                           const float* __restrict__ word_table,
                                           const float* __restrict__ sem_table,
                                           const short* __restrict__ WcatP,
                                           const float* __restrict__ bih_f,
                                           const float* __restrict__ bhh_f,
                                           const float* __restrict__ bih_b,
                                           const float* __restrict__ bhh_b,
                                           float* __restrict__ P1,
                                           float* __restrict__ P2)
{
    __shared__ __align__(16) short As[128 * LDT];
    __shared__ __align__(16) short Bs[128 * LDT];
    __shared__ const float* rowp[128];

    const int mb = blockIdx.x;
    const int p  = (mb >= 8);
    const int m0 = (p ? mb - 8 : mb) * 128;
    const int n0 = blockIdx.y * 128;
    const int tid = threadIdx.x;

    if (tid < 128) {
        int m = m0 + tid;
        rowp[tid] = p ? (m < 2186 ? sem_table + (size_t)m * E_ : (const float*)0)
                      : word_table + (size_t)word[m] * E_;
    }
    __syncthreads();

    f32x4 acc[4][4];
    #pragma unroll
    for (int i = 0; i < 4; ++i)
        #pragma unroll
        for (int j = 0; j < 4; ++j)
            acc[i][j] = (f32x4){0.f, 0.f, 0.f, 0.f};

    const int wv   = tid >> 6;
    const int lane = tid & 63;
    const int wm   = (wv >> 1) * 64;
    const int wn   = (wv & 1) * 64;
    const int lm   = lane & 15;
    const int quad = lane >> 4;

    const int r  = tid >> 1;
    const int kh = (tid & 1) * 16;
    const float* rp = rowp[r];
    const short* bsrc = WcatP + (size_t)p * (NPAD * 320) + (size_t)(n0 + r) * 320;

    for (int k0 = 0; k0 < 320; k0 += 32) {
        {
            const int kbase = k0 + kh;
            #pragma unroll
            for (int q = 0; q < 4; ++q) {
                int k = kbase + q * 4;
                float4 v = (k < E_ && rp) ? *(const float4*)&rp[k]
                                          : make_float4(0.f, 0.f, 0.f, 0.f);
                short4 s4;
                s4.x = f2bf(v.x); s4.y = f2bf(v.y);
                s4.z = f2bf(v.z); s4.w = f2bf(v.w);
                *(short4*)&As[r * LDT + kh + q * 4] = s4;
            }
        }
        {
            const short* src = bsrc + k0 + kh;
            *(int4*)&Bs[r * LDT + kh + 0] = *(const int4*)&src[0];
            *(int4*)&Bs[r * LDT + kh + 8] = *(const int4*)&src[8];
        }
        __syncthreads();

        bf16x8 af[4], bfr[4];
        #pragma unroll
        for (int i = 0; i < 4; ++i)
            af[i] = *(const bf16x8*)&As[(wm + 16 * i + lm) * LDT + quad * 8];
        #pragma unroll
        for (int j = 0; j < 4; ++j)
            bfr[j] = *(const bf16x8*)&Bs[(wn + 16 * j + lm) * LDT + quad * 8];
        #pragma unroll
        for (int i = 0; i < 4; ++i)
            #pragma unroll
            for (int j = 0; j < 4; ++j)
                acc[i][j] = __builtin_amdgcn_mfma_f32_16x16x32_bf16(
                    af[i], bfr[j], acc[i][j], 0, 0, 0);
        __syncthreads();
    }

    float* dst = p ? P2 : P1;
    #pragma unroll
    for (int j = 0; j < 4; ++j) {
        int n = n0 + wn + 16 * j + lm;
        float bias = 0.f;
        if (p) {
            int fwd = (n < 1216);
            int cc = fwd ? n : n - 1216;
            if (cc < G4_) {
                int u = cc >> 2, g = cc & 3;
                bias = fwd ? (bih_f[g * 300 + u] + bhh_f[g * 300 + u])
                           : (bih_b[g * 300 + u] + bhh_b[g * 300 + u]);
            }
        }
        #pragma unroll
        for (int i = 0; i < 4; ++i) {
            int mb2 = m0 + wm + 16 * i + quad * 4;
            #pragma unroll
            for (int reg = 0; reg < 4; ++reg)
                dst[(size_t)(mb2 + reg) * PSTR + n] = acc[i][j][reg] + bias;
        }
    }
}

// ---------------------------------------------------------------------------
// k_rec3: batch-partitioned recurrence. NO grid sync, NO cooperative launch.
// Grid (32, 2): block owns 32 batch rows x 1 direction, computes ALL 300
// units for its rows across all 18 steps. h lives in a block-local LDS
// fragment buffer; c lives in per-thread LDS slots. Whh B-frags stream from
// L2 each step (~760 KB/CU/step) with triple-buffered register prefetch.
//
// amdgpu_waves_per_eu(2,2): pin occupancy at exactly 2 waves/SIMD -> true
// 256-VGPR budget. r3/r4 evidence: launch_bounds(512,2) only sets a MINIMUM
// occupancy (cap 256) but the backend's heuristic still targeted 4 waves/SIMD
// and squeezed to exactly 128 VGPRs (r3+r4: VGPR_Count=128, 503us, MfmaUtil
// 2%) -- sinking/spilling the ~190-reg triple-buffer pipeline. Pinning (2,2)
// removes the incentive. 512-thr blocks at 1 block/CU are 2 waves/SIMD anyway.
//
// xv double-buffer: body I issues the P1/P2 gather for body I+1 (+16 VGPRs).
// The svt-gather is HBM-miss-heavy (~900cy, 231MB/dispatch random rows);
// consuming one body later (~600-1000cy) covers it.
//
// Swapped-operand MFMA: acc = mfma(W_frag, h_frag) makes D row = gate axis.
// With the 4u+g gate interleave, lane l's f32x4 acc holds gates i,f,g,o
// (regs 0..3) of unit nt*4+(l>>4) for batch row (l&15) -> cell math is
// fully in-register, no LDS redistribution, no cross-lane ops.
//
// Wave roles (8 waves): nq = wv&3 owns N-quarter (19 nt tiles = 76 units),
// mt = wv>>2 owns a 16-row batch half.
//
// Triple-buffer schedule: at iteration I, buffer (I%3) holds tile T_I; we
// prefetch T_{I+2} into buffer ((I+2)%3), which was freed at I-1.
// ---------------------------------------------------------------------------
#define NT_BODY(I, BCUR, BNXT, PF)                                            \
  {                                                                           \
    if (PF) {                                                                 \
      const short* wn = wfp + (size_t)((I) + 2) * 5120;                       \
      _Pragma("unroll")                                                       \
      for (int kt = 0; kt < 10; ++kt)                                         \
        BNXT[kt] = *(const bf16x8*)(wn + kt * 512);                           \
    }                                                                         \
    if ((I) < 18) {                                                           \
      x2b[((I) + 1) & 1] = *(const float4*)(p2r + 16 * ((I) + 1));            \
      float4 t1 = make_float4(0.f, 0.f, 0.f, 0.f);                            \
      if (svt != 0) t1 = *(const float4*)(p1r + 16 * ((I) + 1));              \
      x1b[((I) + 1) & 1] = t1;                                                \
    }                                                                         \
    f32x4 acc = (f32x4){0.f, 0.f, 0.f, 0.f};                                  \
    if (s > 0) {                                                              \
      _Pragma("unroll")                                                       \
      for (int kt = 0; kt < 10; ++kt)                                         \
        acc = __builtin_amdgcn_mfma_f32_16x16x32_bf16(BCUR[kt], af[kt],       \
                                                      acc, 0, 0, 0);          \
    }                                                                         \
    float gi  = x2b[(I) & 1].x + x1b[(I) & 1].x + acc[0];                     \
    float gf  = x2b[(I) & 1].y + x1b[(I) & 1].y + acc[1];                     \
    float gg2 = x2b[(I) & 1].z + x1b[(I) & 1].z + acc[2];                     \
    float go  = x2b[(I) & 1].w + x1b[(I) & 1].w + acc[3];                     \
    float iv = 1.f / (1.f + __expf(-gi));                                     \
    float fv = 1.f / (1.f + __expf(-gf));                                     \
    float tg = 1.f - 2.f / (__expf(2.f * gg2) + 1.f);                         \
    float ov = 1.f / (1.f + __expf(-go));                                     \
    float cc = fmaf(fv, cst[cslot + (I)], iv * tg);                           \
    cst[cslot + (I)] = cc;                                                    \
    float th = 1.f - 2.f / (__expf(2.f * cc) + 1.f);                          \
    short hv = f2bf(ov * th);                                                 \
    int u = unt0 + 4 * (I);                                                   \
    hbuf[(mt * 10 + (u >> 5)) * 512 + ((lr | (((u >> 3) & 3) << 4)) << 3)     \
         + (u & 7)] = hv;                                                     \
    hcrow[u] = hv;                                                            \
  }

__global__ __launch_bounds__(512)
__attribute__((amdgpu_waves_per_eu(2, 2)))
void k_rec3(const float* __restrict__ P1,
            const float* __restrict__ P2,
            const int* __restrict__ sem,
            const short* __restrict__ WFf,
            const short* __restrict__ WFb,
            short* __restrict__ hcat)
{
    const int d = blockIdx.y;
    const short* WF = d ? WFb : WFf;
    short* hc = hcat + (d ? 304 : 0);

    const int b0   = blockIdx.x * 32;
    const int tid  = threadIdx.x;
    const int lane = tid & 63;
    const int wv   = tid >> 6;
    const int nq   = wv & 3;          // N-quarter: nt = nq*19 + i
    const int mt   = wv >> 2;         // batch half (16 rows)
    const int lr   = lane & 15;       // batch row within tile (= D col)
    const int lu   = lane >> 4;       // unit sub-index within nt tile
    const int b    = b0 + mt * 16 + lr;
    const int unt0 = nq * 76 + lu;    // u = unt0 + 4*i
    const int cslot = tid * 19;

    // LDS: h fragment buffer (frag layout [mt][kt][512]) + per-thread c slots
    __shared__ __align__(16) short hbuf[2 * 10 * 512];    // 20 KB
    __shared__ __align__(16) float cst[512 * 19];         // 38.9 KB

    // zero-init (pad fragment zones must be 0; c starts at 0)
    for (int idx = tid; idx < 1280; idx += 512)
        ((int4*)hbuf)[idx] = make_int4(0, 0, 0, 0);
    for (int idx = tid; idx < 2432; idx += 512)
        ((float4*)cst)[idx] = make_float4(0.f, 0.f, 0.f, 0.f);
    __syncthreads();

    // per-thread invariant pointers
    const size_t pbase = (size_t)d * 1216 + (size_t)nq * 304 + (size_t)lu * 4;
    const float* p1r = P1 + (size_t)b * PSTR + pbase;
    const float* p2b = P2 + pbase;
    const short* wfp = WF + (size_t)(nq * 19) * 5120 + (size_t)lane * 8;

    #pragma unroll 1
    for (int s = 0; s < L_; ++s) {
        const int t = d ? (L_ - 1 - s) : s;
        const int svt = sem[b * L_ + t];
        const float* p2r = p2b + (size_t)svt * PSTR;
        short* hcrow = hc + ((size_t)b * L_ + t) * 608;

        // prime the xv double-buffer (body 0's gather)
        float4 x2b[2], x1b[2];
        x2b[0] = *(const float4*)(p2r);
        {
            float4 t1 = make_float4(0.f, 0.f, 0.f, 0.f);
            if (svt != 0) t1 = *(const float4*)(p1r);
            x1b[0] = t1;
        }

        // prime the triple-buffered Whh B-frag pipeline (global, L2-hit)
        bf16x8 bA[10], bB[10], bC[10];
        #pragma unroll
        for (int kt = 0; kt < 10; ++kt)
            bA[kt] = *(const bf16x8*)(wfp + kt * 512);
        #pragma unroll
        for (int kt = 0; kt < 10; ++kt)
            bB[kt] = *(const bf16x8*)(wfp + 5120 + kt * 512);

        // read this step's A-frags (h from previous step) before the barrier
        bf16x8 af[10];
        if (s > 0) {
            const short* hb = hbuf + mt * 5120 + lane * 8;
            #pragma unroll
            for (int kt = 0; kt < 10; ++kt)
                af[kt] = *(const bf16x8*)(hb + kt * 512);
        }
        __syncthreads();   // all A-frag reads done before anyone rewrites hbuf

        #pragma unroll 1
        for (int i = 0; i < 18; i += 3) {
            NT_BODY(i,     bA, bC, 1)
            NT_BODY(i + 1, bB, bA, 1)
            NT_BODY(i + 2, bC, bB, (i < 15))
        }
        NT_BODY(18, bA, bC, 0)

        __syncthreads();   // h(s) complete in hbuf before step s+1 reads it
    }
}

// ---------------------------------------------------------------------------
// k_out: V = relu(hcat @ WAT^T + ba)  bf16 MFMA.  M=18432, N=304(300), K=608.
// ---------------------------------------------------------------------------
__global__ __launch_bounds__(256) void k_out(const short* __restrict__ hcat,
                                             const short* __restrict__ WAT,
                                             const float* __restrict__ ba,
                                             float* __restrict__ out)
{
    const int m0 = blockIdx.x * 64;
    const int tid = threadIdx.x;
    const int lane = tid & 63;
    const int wv = tid >> 6;
    const int lm = lane & 15;
    const int quad = lane >> 4;

    __shared__ __align__(16) short A_s[64][616];

    for (int idx = tid; idx < 4864; idx += 256) {   // 64 rows * 76 chunks
        int r = idx / 76, c8 = idx - r * 76;
        *(int4*)&A_s[r][c8 * 8] = *(const int4*)&hcat[(size_t)(m0 + r) * 608 + c8 * 8];
    }
    __syncthreads();

    f32x4 acc[4][5];
    #pragma unroll
    for (int mt = 0; mt < 4; ++mt)
        #pragma unroll
        for (int q = 0; q < 5; ++q)
            acc[mt][q] = (f32x4){0.f, 0.f, 0.f, 0.f};

    for (int kt = 0; kt < 19; ++kt) {
        bf16x8 af[4];
        #pragma unroll
        for (int mt = 0; mt < 4; ++mt)
            af[mt] = *(const bf16x8*)&A_s[mt * 16 + lm][kt * 32 + quad * 8];
        #pragma unroll
        for (int q = 0; q < 5; ++q) {
            int nt = wv + 4 * q;
            if (nt < 19) {
                bf16x8 bf = *(const bf16x8*)&WAT[((size_t)(nt * 19 + kt) * 64 + lane) * 8];
                #pragma unroll
                for (int mt = 0; mt < 4; ++mt)
                    acc[mt][q] = __builtin_amdgcn_mfma_f32_16x16x32_bf16(
                        af[mt], bf, acc[mt][q], 0, 0, 0);
            }
        }
    }

    #pragma unroll
    for (int q = 0; q < 5; ++q) {
        int nt = wv + 4 * q;
        if (nt < 19) {
            int o = nt * 16 + lm;
            if (o < H_) {
                float bias = ba[o];
                #pragma unroll
                for (int mt = 0; mt < 4; ++mt) {
                    #pragma unroll
                    for (int r = 0; r < 4; ++r) {
                        int m = m0 + mt * 16 + quad * 4 + r;
                        float v = acc[mt][q][r] + bias;
                        out[(size_t)m * H_ + o] = v > 0.f ? v : 0.f;
                    }
                }
            }
        }
    }
}

// ---------------------------------------------------------------------------
extern "C" void kernel_launch(void* const* d_in, const int* in_sizes, int n_in,
                              void* d_out, int out_size, void* d_ws, size_t ws_size,
                              hipStream_t stream) {
    const int*   word       = (const int*)  d_in[0];
    const int*   sem        = (const int*)  d_in[1];
    const float* word_table = (const float*)d_in[2];
    const float* sem_table  = (const float*)d_in[3];
    const float* Wih_f      = (const float*)d_in[4];
    const float* Whh_f      = (const float*)d_in[5];
    const float* bih_f      = (const float*)d_in[6];
    const float* bhh_f      = (const float*)d_in[7];
    const float* Wih_b      = (const float*)d_in[8];
    const float* Whh_b      = (const float*)d_in[9];
    const float* bih_b      = (const float*)d_in[10];
    const float* bhh_b      = (const float*)d_in[11];
    const float* Wa         = (const float*)d_in[12];
    const float* ba         = (const float*)d_in[13];
    const float* Wb         = (const float*)d_in[14];
    const float* bbv        = (const float*)d_in[15];

    float* out = (float*)d_out;
    float* ws  = (float*)d_ws;

    float* P1    = ws + OFF_P1;
    float* P2    = ws + OFF_P2;
    short* hcat  = (short*)(ws + OFF_HCAT);
    float* ag    = ws + OFF_AG;
    float* WbT   = ws + OFF_WBT;
    short* WFf   = (short*)(ws + OFF_WFF);
    short* WFb   = (short*)(ws + OFF_WFB);
    short* WAT   = (short*)(ws + OFF_WAT);
    short* WcatP = (short*)(ws + OFF_WCP);

    // weight re-layouts (every call; inputs restored each launch)
    k_prep<<<dim3(352), dim3(256), 0, stream>>>(Wb, WbT);
    k_prep_wcp<<<dim3((2 * NPAD * 320 + 255) / 256), dim3(256), 0, stream>>>(
        Wih_f, Wih_b, WcatP);
    k_prep_whh<<<dim3(1520, 2), dim3(256), 0, stream>>>(Whh_f, Whh_b, WFf, WFb);
    k_prep_wa<<<dim3(722), dim3(256), 0, stream>>>(Wa, WAT);

    // v_g branch
    k_ag<<<dim3(B_), dim3(256), 0, stream>>>(sem, sem_table, ag);
    k_vg<<<dim3(B_ / 16), dim3(256), 0, stream>>>(ag, WbT, bbv, out);

    // factored input GEMMs: P1 (word part) + P2' (sememe part + bias)
    k_p<<<dim3(26, 19), dim3(256), 0, stream>>>(
        word, word_table, sem_table, WcatP,
        bih_f, bhh_f, bih_b, bhh_b, P1, P2);

    // recurrence: batch-partitioned, block-local h/c, no grid sync
    k_rec3<<<dim3(32, 2), dim3(512), 0, stream>>>(P1, P2, sem, WFf, WFb, hcat);

    // output projection (bf16 MFMA)
    k_out<<<dim3(M_ / 64), dim3(256), 0, stream>>>(hcat, WAT, ba, out);
}

// Round 6
// 857.638 us; speedup vs baseline: 1.0131x; 1.0131x over previous
//
#include <hip/hip_runtime.h>
#include <cstddef>
#include <cstdint>
#include <math.h>

#define B_   1024
#define L_   18
#define E_   300
#define H_   300
#define M_   (B_*L_)     // 18432 rows (b,l)
#define G4_  (4*H_)      // 1200
#define K2E_ (2*E_)      // 600

#define NPAD 2432        // gate-interleaved cols, both dirs (2*1216)
#define PSTR 2432        // P1/P2 row stride (fp32)
#define M2P  2304        // P2 padded rows (2186 valid)

// workspace layout (float offsets)
#define OFF_P1   ((size_t)0)                         // fp32 1024x2432
#define OFF_P2   (OFF_P1 + (size_t)1024*PSTR)        // fp32 2304x2432 (+bias)
#define OFF_HCAT (OFF_P2 + (size_t)M2P*PSTR)         // bf16 18432x608
#define OFF_AG   (OFF_HCAT + (size_t)M_*608/2)
#define OFF_WBT  (OFF_AG  + (size_t)B_*E_)
#define OFF_WFF  (OFF_WBT + 90000)                   // bf16 76x10x512 B-frag
#define OFF_WFB  (OFF_WFF + 194560)
#define OFF_WAT  (OFF_WFB + 194560)                  // bf16 19x19x512 B-frag
#define OFF_WCP  (OFF_WAT + 92416)                   // bf16 2x2432x320

#define VOFF ((size_t)M_*H_)  // v_g offset in d_out

typedef short bf16x8 __attribute__((ext_vector_type(8)));
typedef float f32x4  __attribute__((ext_vector_type(4)));

__device__ __forceinline__ short f2bf(float f) {
    union { float f; uint32_t u; } c; c.f = f;
    uint32_t u = c.u + 0x7fffu + ((c.u >> 16) & 1u);   // RNE
    return (short)(u >> 16);
}

// ---------------------------------------------------------------------------
// WbT[k][o] = Wb[o*300 + k]
// ---------------------------------------------------------------------------
__global__ void k_prep(const float* __restrict__ Wb, float* __restrict__ WbT)
{
    int idx = blockIdx.x * 256 + threadIdx.x;
    if (idx < 90000) {
        int o = idx % 300;
        int k = idx / 300;
        WbT[idx] = Wb[o * 300 + k];
    }
}

// ---------------------------------------------------------------------------
// WcatP[p][n'][kp] bf16: p=0 -> Wih[:, kp], p=1 -> Wih[:, 300+kp].
// n' gate-interleaved: n'<1216 fwd (n'=4u+g -> row g*300+u), else bwd.
// ---------------------------------------------------------------------------
__global__ __launch_bounds__(256) void k_prep_wcp(const float* __restrict__ Wih_f,
                                                  const float* __restrict__ Wih_b,
                                                  short* __restrict__ WcatP)
{
    int idx = blockIdx.x * 256 + threadIdx.x;   // < 2*2432*320
    if (idx >= 2 * NPAD * 320) return;
    int p = idx / (NPAD * 320);
    int rem = idx - p * (NPAD * 320);
    int n = rem / 320;
    int kp = rem - n * 320;
    int fwd = (n < 1216);
    int nn = fwd ? n : n - 1216;
    float v = 0.f;
    if (kp < 300 && nn < G4_) {
        int u = nn >> 2, g = nn & 3;
        const float* W = fwd ? Wih_f : Wih_b;
        v = W[(size_t)(g * 300 + u) * K2E_ + (p ? 300 + kp : kp)];
    }
    WcatP[idx] = f2bf(v);
}

// ---------------------------------------------------------------------------
// Whh B-fragment pack: WF[d][(nt*10+kt)*512 + lane*8 + j] =
//   bf16(Whh_d[(g*300+u)*300 + k]),  n = nt*16+(lane&15) = 4u+g,
//   k = kt*32 + (lane>>4)*8 + j; zero pads.
// ---------------------------------------------------------------------------
__global__ __launch_bounds__(256) void k_prep_whh(const float* __restrict__ Whh_f,
                                                  const float* __restrict__ Whh_b,
                                                  short* __restrict__ WFf,
                                                  short* __restrict__ WFb)
{
    int idx = blockIdx.x * 256 + threadIdx.x;   // < 389120
    if (idx >= 389120) return;
    int d = blockIdx.y;
    int chunk = idx >> 9;           // nt*10+kt
    int rem   = idx & 511;
    int lane  = rem >> 3;
    int j     = rem & 7;
    int nt = chunk / 10, kt = chunk - nt * 10;
    int n = nt * 16 + (lane & 15);
    int k = kt * 32 + (lane >> 4) * 8 + j;
    float v = 0.f;
    if (n < G4_ && k < H_) {
        int u = n >> 2, g = n & 3;
        const float* W = d ? Whh_b : Whh_f;
        v = W[(size_t)(g * 300 + u) * H_ + k];
    }
    (d ? WFb : WFf)[idx] = f2bf(v);
}

// ---------------------------------------------------------------------------
// Wa B-fragment pack for k_out: N=304 (19 nt), K=608 (19 kt).
// ---------------------------------------------------------------------------
__global__ __launch_bounds__(256) void k_prep_wa(const float* __restrict__ Wa,
                                                 short* __restrict__ WAT)
{
    int idx = blockIdx.x * 256 + threadIdx.x;   // < 184832
    if (idx >= 184832) return;
    int chunk = idx >> 9;           // nt*19+kt
    int rem   = idx & 511;
    int lane  = rem >> 3;
    int j     = rem & 7;
    int nt = chunk / 19, kt = chunk - nt * 19;
    int o  = nt * 16 + (lane & 15);
    int kp = kt * 32 + (lane >> 4) * 8 + j;
    float v = 0.f;
    if (o < H_) {
        int k = -1;
        if (kp < 300)                   k = kp;
        else if (kp >= 304 && kp < 604) k = kp - 4;
        if (k >= 0) v = Wa[(size_t)o * K2E_ + k];
    }
    WAT[idx] = f2bf(v);
}

// ---------------------------------------------------------------------------
// a_g[b][e] = mean_l sem_table[sememes[b][l]][e]
// ---------------------------------------------------------------------------
__global__ __launch_bounds__(256) void k_ag(const int* __restrict__ sem,
                                            const float* __restrict__ sem_table,
                                            float* __restrict__ ag)
{
    int b = blockIdx.x;
    __shared__ int sm[L_];
    if (threadIdx.x < L_) sm[threadIdx.x] = sem[b * L_ + threadIdx.x];
    __syncthreads();
    for (int e = threadIdx.x; e < E_; e += 256) {
        float s = 0.f;
        #pragma unroll
        for (int l = 0; l < L_; ++l) s += sem_table[sm[l] * E_ + e];
        ag[(size_t)b * E_ + e] = s * (1.0f / (float)L_);
    }
}

// ---------------------------------------------------------------------------
// v_g = relu(a_g @ Wb^T + bb) -> d_out[VOFF + ...]
// ---------------------------------------------------------------------------
__global__ __launch_bounds__(256) void k_vg(const float* __restrict__ ag,
                                            const float* __restrict__ WbT,
                                            const float* __restrict__ bbv,
                                            float* __restrict__ out)
{
    int b0 = blockIdx.x * 16;
    __shared__ __align__(16) float ag_s[16 * E_];
    for (int idx = threadIdx.x; idx < 16 * E_; idx += 256)
        ag_s[idx] = ag[(size_t)b0 * E_ + idx];
    __syncthreads();
    for (int o = threadIdx.x; o < E_; o += 256) {
        float acc[16];
        #pragma unroll
        for (int i = 0; i < 16; ++i) acc[i] = 0.f;
        for (int k = 0; k < E_; ++k) {
            float w = WbT[k * E_ + o];
            #pragma unroll
            for (int i = 0; i < 16; ++i)
                acc[i] = fmaf(w, ag_s[i * E_ + k], acc[i]);
        }
        float bias = bbv[o];
        #pragma unroll
        for (int i = 0; i < 16; ++i) {
            float v = acc[i] + bias;
            out[VOFF + (size_t)(b0 + i) * E_ + o] = v > 0.f ? v : 0.f;
        }
    }
}

// ---------------------------------------------------------------------------
// k_p: P1 = w @ Wih1^T  (rows 0..1023, mb 0..7)
//      P2' = sem_table @ Wih2^T + bias  (rows 0..2303, mb 8..25)
// bf16 MFMA, 128x128 tiles, K=320 (300 valid). Grid (26, 19).
// ---------------------------------------------------------------------------
#define LDT 40

__global__ __launch_bounds__(256) void k_p(const int* __restrict__ word,
                                           const float* __restrict__ word_table,
                                           const float* __restrict__ sem_table,
                                           const short* __restrict__ WcatP,
                                           const float* __restrict__ bih_f,
                                           const float* __restrict__ bhh_f,
                                           const float* __restrict__ bih_b,
                                           const float* __restrict__ bhh_b,
                                           float* __restrict__ P1,
                                           float* __restrict__ P2)
{
    __shared__ __align__(16) short As[128 * LDT];
    __shared__ __align__(16) short Bs[128 * LDT];
    __shared__ const float* rowp[128];

    const int mb = blockIdx.x;
    const int p  = (mb >= 8);
    const int m0 = (p ? mb - 8 : mb) * 128;
    const int n0 = blockIdx.y * 128;
    const int tid = threadIdx.x;

    if (tid < 128) {
        int m = m0 + tid;
        rowp[tid] = p ? (m < 2186 ? sem_table + (size_t)m * E_ : (const float*)0)
                      : word_table + (size_t)word[m] * E_;
    }
    __syncthreads();

    f32x4 acc[4][4];
    #pragma unroll
    for (int i = 0; i < 4; ++i)
        #pragma unroll
        for (int j = 0; j < 4; ++j)
            acc[i][j] = (f32x4){0.f, 0.f, 0.f, 0.f};

    const int wv   = tid >> 6;
    const int lane = tid & 63;
    const int wm   = (wv >> 1) * 64;
    const int wn   = (wv & 1) * 64;
    const int lm   = lane & 15;
    const int quad = lane >> 4;

    const int r  = tid >> 1;
    const int kh = (tid & 1) * 16;
    const float* rp = rowp[r];
    const short* bsrc = WcatP + (size_t)p * (NPAD * 320) + (size_t)(n0 + r) * 320;

    for (int k0 = 0; k0 < 320; k0 += 32) {
        {
            const int kbase = k0 + kh;
            #pragma unroll
            for (int q = 0; q < 4; ++q) {
                int k = kbase + q * 4;
                float4 v = (k < E_ && rp) ? *(const float4*)&rp[k]
                                          : make_float4(0.f, 0.f, 0.f, 0.f);
                short4 s4;
                s4.x = f2bf(v.x); s4.y = f2bf(v.y);
                s4.z = f2bf(v.z); s4.w = f2bf(v.w);
                *(short4*)&As[r * LDT + kh + q * 4] = s4;
            }
        }
        {
            const short* src = bsrc + k0 + kh;
            *(int4*)&Bs[r * LDT + kh + 0] = *(const int4*)&src[0];
            *(int4*)&Bs[r * LDT + kh + 8] = *(const int4*)&src[8];
        }
        __syncthreads();

        bf16x8 af[4], bfr[4];
        #pragma unroll
        for (int i = 0; i < 4; ++i)
            af[i] = *(const bf16x8*)&As[(wm + 16 * i + lm) * LDT + quad * 8];
        #pragma unroll
        for (int j = 0; j < 4; ++j)
            bfr[j] = *(const bf16x8*)&Bs[(wn + 16 * j + lm) * LDT + quad * 8];
        #pragma unroll
        for (int i = 0; i < 4; ++i)
            #pragma unroll
            for (int j = 0; j < 4; ++j)
                acc[i][j] = __builtin_amdgcn_mfma_f32_16x16x32_bf16(
                    af[i], bfr[j], acc[i][j], 0, 0, 0);
        __syncthreads();
    }

    float* dst = p ? P2 : P1;
    #pragma unroll
    for (int j = 0; j < 4; ++j) {
        int n = n0 + wn + 16 * j + lm;
        float bias = 0.f;
        if (p) {
            int fwd = (n < 1216);
            int cc = fwd ? n : n - 1216;
            if (cc < G4_) {
                int u = cc >> 2, g = cc & 3;
                bias = fwd ? (bih_f[g * 300 + u] + bhh_f[g * 300 + u])
                           : (bih_b[g * 300 + u] + bhh_b[g * 300 + u]);
            }
        }
        #pragma unroll
        for (int i = 0; i < 4; ++i) {
            int mb2 = m0 + wm + 16 * i + quad * 4;
            #pragma unroll
            for (int reg = 0; reg < 4; ++reg)
                dst[(size_t)(mb2 + reg) * PSTR + n] = acc[i][j][reg] + bias;
        }
    }
}

// ---------------------------------------------------------------------------
// k_rec4: batch x unit partitioned recurrence, asm-pinned VMEM pipeline.
//
// Grid (64, 2) x 512 thr. Block owns 16 batch rows x 1 direction; the 8
// waves split the 76 unit-tiles 8 ways (10 tiles each, tile0=(wv*76)>>3,
// seam tiles duplicated -> idempotent). NO intra-step barriers: waves only
// exchange h at step boundaries (2 x __syncthreads per step). c in registers.
//
// r3-r5 lesson: the compiler SINKS normal weight loads to their uses (VGPR
// stayed 128 with a 256 budget available), serializing every body on L2
// latency; and small indexed arrays get alloca-promoted to LDS (r5: +32KB
// LDS, 4.5M bank conflicts). Fix: EVERY global access in the step loop is
// inline asm (un-sinkable, mutually ordered) with hand-counted s_waitcnt
// vmcnt(N), each followed by sched_barrier(0) (rule #18: MFMA can hoist past
// asm waitcnt). Explicit vmcnt(0) before the step barrier because the
// compiler's waitcnt pass cannot see asm loads.
//
// Steady-state per body I (1..8): enter with [wf(I) x10, xv(I) x2, st(I-1) x1]
// outstanding; issue wf(I+1) x10 + xv(I+1) x2; vmcnt(15) drains wf(I);
// 10 MFMA; vmcnt(13) drains xv(I); cell math; 1 store. Body 0: no waits
// (drained by step-top vmcnt(0)+barrier). Body 9: no issue, vmcnt(3)/vmcnt(1).
// ---------------------------------------------------------------------------
#define VMWAIT(N)                                                             \
    asm volatile("s_waitcnt vmcnt(%0)" :: "n"(N) : "memory");                 \
    __builtin_amdgcn_sched_barrier(0)

#define WFLOAD(DST, I)                                                        \
  { _Pragma("unroll")                                                         \
    for (int kt_ = 0; kt_ < 10; ++kt_) {                                      \
      const short* wp_ = wfp + (size_t)(I) * 5120 + kt_ * 512;                \
      asm volatile("global_load_dwordx4 %0, %1, off"                          \
                   : "=v"(DST[kt_]) : "v"(wp_) : "memory");                   \
    } }

#define XVLOAD(X2, X1, I)                                                     \
  { const float* a2_ = p2r + 16 * (I);                                        \
    asm volatile("global_load_dwordx4 %0, %1, off"                            \
                 : "=v"(X2) : "v"(a2_) : "memory");                           \
    const float* a1_ = p1r + 16 * (I);                                        \
    asm volatile("global_load_dwordx4 %0, %1, off"                            \
                 : "=v"(X1) : "v"(a1_) : "memory"); }

#define BODYW(I, WCUR, WNXT, X2C, X1C, X2N, X1N, PF, DOW, WM, WC)             \
  {                                                                           \
    if (PF) { WFLOAD(WNXT, (I) + 1) XVLOAD(X2N, X1N, (I) + 1) }               \
    if (DOW) { VMWAIT(WM); }                                                  \
    f32x4 acc = (f32x4){0.f, 0.f, 0.f, 0.f};                                  \
    _Pragma("unroll")                                                         \
    for (int kt_ = 0; kt_ < 10; ++kt_)                                        \
      acc = __builtin_amdgcn_mfma_f32_16x16x32_bf16(WCUR[kt_], af[kt_],       \
                                                    acc, 0, 0, 0);            \
    if (DOW) { VMWAIT(WC); }                                                  \
    float gi  = X2C.x + msk * X1C.x + acc[0];                                 \
    float gf  = X2C.y + msk * X1C.y + acc[1];                                 \
    float gg2 = X2C.z + msk * X1C.z + acc[2];                                 \
    float go  = X2C.w + msk * X1C.w + acc[3];                                 \
    float iv = 1.f / (1.f + __expf(-gi));                                     \
    float fv = 1.f / (1.f + __expf(-gf));                                     \
    float tg = 1.f - 2.f / (__expf(2.f * gg2) + 1.f);                         \
    float ov = 1.f / (1.f + __expf(-go));                                     \
    float cc = fmaf(fv, c[(I)], iv * tg);                                     \
    c[(I)] = cc;                                                              \
    float th = 1.f - 2.f / (__expf(2.f * cc) + 1.f);                          \
    short hv = f2bf(ov * th);                                                 \
    int u_ = unt0 + 4 * (I);                                                  \
    hbuf[(u_ >> 5) * 512 + ((lr | (((u_ >> 3) & 3) << 4)) << 3) + (u_ & 7)] = hv; \
    int hvi_ = (unsigned short)hv;                                            \
    asm volatile("global_store_short %0, %1, off offset:%2"                   \
                 :: "v"(hcp), "v"(hvi_), "n"(8 * (I)) : "memory");            \
  }

__global__ __launch_bounds__(512)
__attribute__((amdgpu_waves_per_eu(2, 2)))
void k_rec4(const float* __restrict__ P1,
            const float* __restrict__ P2,
            const int* __restrict__ sem,
            const short* __restrict__ WFf,
            const short* __restrict__ WFb,
            short* __restrict__ hcat)
{
    const int d = blockIdx.y;
    const short* WF = d ? WFb : WFf;
    short* hc = hcat + (d ? 304 : 0);

    const int b0    = blockIdx.x * 16;
    const int tid   = threadIdx.x;
    const int lane  = tid & 63;
    const int wv    = tid >> 6;
    const int lr    = lane & 15;             // batch row (= D col)
    const int lu    = lane >> 4;             // unit sub-index in nt tile
    const int b     = b0 + lr;
    const int tile0 = (wv * 76) >> 3;        // {0,9,19,28,38,47,57,66}
    const int unt0  = tile0 * 4 + lu;        // u = unt0 + 4*i

    __shared__ __align__(16) short hbuf[10 * 512];     // 10 KB, h frag layout

    for (int idx = tid; idx < 640; idx += 512)
        ((int4*)hbuf)[idx] = make_int4(0, 0, 0, 0);

    const size_t pbase = (size_t)d * 1216 + (size_t)tile0 * 16 + (size_t)lu * 4;
    const float* p1r = P1 + (size_t)b * PSTR + pbase;
    const float* p2b = P2 + pbase;
    const short* wfp = WF + (size_t)tile0 * 5120 + (size_t)lane * 8;
    const short* hb  = hbuf + lane * 8;

    float c[10];
    #pragma unroll
    for (int i = 0; i < 10; ++i) c[i] = 0.f;

    bf16x8 wfA[10], wfB[10];
    float4 x2A, x2B, x1A, x1B;

    #pragma unroll 1
    for (int s = 0; s < L_; ++s) {
        __syncthreads();   // sync1: step s-1 hbuf writes visible (full drain)

        const int t = d ? (L_ - 1 - s) : s;
        const int svt = sem[b * L_ + t];
        const float msk = (svt != 0) ? 1.f : 0.f;
        const float* p2r = p2b + (size_t)svt * PSTR;
        short* hcp = hc + ((size_t)b * L_ + t) * 608 + unt0;

        // prime: wf(0) + xv(0) (asm loads, drained below)
        WFLOAD(wfA, 0)
        XVLOAD(x2A, x1A, 0)

        // h(s-1) A-frags (zeros at s=0 from the init)
        bf16x8 af[10];
        #pragma unroll
        for (int kt = 0; kt < 10; ++kt)
            af[kt] = *(const bf16x8*)(hb + kt * 512);

        VMWAIT(0);         // our drain: compiler can't see the asm loads
        __syncthreads();   // sync2: af reads done before bodies rewrite hbuf

        BODYW(0, wfA, wfB, x2A, x1A, x2B, x1B, 1, 0, 0, 0)
        BODYW(1, wfB, wfA, x2B, x1B, x2A, x1A, 1, 1, 15, 13)
        BODYW(2, wfA, wfB, x2A, x1A, x2B, x1B, 1, 1, 15, 13)
        BODYW(3, wfB, wfA, x2B, x1B, x2A, x1A, 1, 1, 15, 13)
        BODYW(4, wfA, wfB, x2A, x1A, x2B, x1B, 1, 1, 15, 13)
        BODYW(5, wfB, wfA, x2B, x1B, x2A, x1A, 1, 1, 15, 13)
        BODYW(6, wfA, wfB, x2A, x1A, x2B, x1B, 1, 1, 15, 13)
        BODYW(7, wfB, wfA, x2B, x1B, x2A, x1A, 1, 1, 15, 13)
        BODYW(8, wfA, wfB, x2A, x1A, x2B, x1B, 1, 1, 15, 13)
        BODYW(9, wfB, wfA, x2B, x1B, x2A, x1A, 0, 1, 3, 1)
    }
}

// ---------------------------------------------------------------------------
// k_out: V = relu(hcat @ WAT^T + ba)  bf16 MFMA.  M=18432, N=304(300), K=608.
// ---------------------------------------------------------------------------
__global__ __launch_bounds__(256) void k_out(const short* __restrict__ hcat,
                                             const short* __restrict__ WAT,
                                             const float* __restrict__ ba,
                                             float* __restrict__ out)
{
    const int m0 = blockIdx.x * 64;
    const int tid = threadIdx.x;
    const int lane = tid & 63;
    const int wv = tid >> 6;
    const int lm = lane & 15;
    const int quad = lane >> 4;

    __shared__ __align__(16) short A_s[64][616];

    for (int idx = tid; idx < 4864; idx += 256) {   // 64 rows * 76 chunks
        int r = idx / 76, c8 = idx - r * 76;
        *(int4*)&A_s[r][c8 * 8] = *(const int4*)&hcat[(size_t)(m0 + r) * 608 + c8 * 8];
    }
    __syncthreads();

    f32x4 acc[4][5];
    #pragma unroll
    for (int mt = 0; mt < 4; ++mt)
        #pragma unroll
        for (int q = 0; q < 5; ++q)
            acc[mt][q] = (f32x4){0.f, 0.f, 0.f, 0.f};

    for (int kt = 0; kt < 19; ++kt) {
        bf16x8 af[4];
        #pragma unroll
        for (int mt = 0; mt < 4; ++mt)
            af[mt] = *(const bf16x8*)&A_s[mt * 16 + lm][kt * 32 + quad * 8];
        #pragma unroll
        for (int q = 0; q < 5; ++q) {
            int nt = wv + 4 * q;
            if (nt < 19) {
                bf16x8 bf = *(const bf16x8*)&WAT[((size_t)(nt * 19 + kt) * 64 + lane) * 8];
                #pragma unroll
                for (int mt = 0; mt < 4; ++mt)
                    acc[mt][q] = __builtin_amdgcn_mfma_f32_16x16x32_bf16(
                        af[mt], bf, acc[mt][q], 0, 0, 0);
            }
        }
    }

    #pragma unroll
    for (int q = 0; q < 5; ++q) {
        int nt = wv + 4 * q;
        if (nt < 19) {
            int o = nt * 16 + lm;
            if (o < H_) {
                float bias = ba[o];
                #pragma unroll
                for (int mt = 0; mt < 4; ++mt) {
                    #pragma unroll
                    for (int r = 0; r < 4; ++r) {
                        int m = m0 + mt * 16 + quad * 4 + r;
                        float v = acc[mt][q][r] + bias;
                        out[(size_t)m * H_ + o] = v > 0.f ? v : 0.f;
                    }
                }
            }
        }
    }
}

// ---------------------------------------------------------------------------
extern "C" void kernel_launch(void* const* d_in, const int* in_sizes, int n_in,
                              void* d_out, int out_size, void* d_ws, size_t ws_size,
                              hipStream_t stream) {
    const int*   word       = (const int*)  d_in[0];
    const int*   sem        = (const int*)  d_in[1];
    const float* word_table = (const float*)d_in[2];
    const float* sem_table  = (const float*)d_in[3];
    const float* Wih_f      = (const float*)d_in[4];
    const float* Whh_f      = (const float*)d_in[5];
    const float* bih_f      = (const float*)d_in[6];
    const float* bhh_f      = (const float*)d_in[7];
    const float* Wih_b      = (const float*)d_in[8];
    const float* Whh_b      = (const float*)d_in[9];
    const float* bih_b      = (const float*)d_in[10];
    const float* bhh_b      = (const float*)d_in[11];
    const float* Wa         = (const float*)d_in[12];
    const float* ba         = (const float*)d_in[13];
    const float* Wb         = (const float*)d_in[14];
    const float* bbv        = (const float*)d_in[15];

    float* out = (float*)d_out;
    float* ws  = (float*)d_ws;

    float* P1    = ws + OFF_P1;
    float* P2    = ws + OFF_P2;
    short* hcat  = (short*)(ws + OFF_HCAT);
    float* ag    = ws + OFF_AG;
    float* WbT   = ws + OFF_WBT;
    short* WFf   = (short*)(ws + OFF_WFF);
    short* WFb   = (short*)(ws + OFF_WFB);
    short* WAT   = (short*)(ws + OFF_WAT);
    short* WcatP = (short*)(ws + OFF_WCP);

    // weight re-layouts (every call; inputs restored each launch)
    k_prep<<<dim3(352), dim3(256), 0, stream>>>(Wb, WbT);
    k_prep_wcp<<<dim3((2 * NPAD * 320 + 255) / 256), dim3(256), 0, stream>>>(
        Wih_f, Wih_b, WcatP);
    k_prep_whh<<<dim3(1520, 2), dim3(256), 0, stream>>>(Whh_f, Whh_b, WFf, WFb);
    k_prep_wa<<<dim3(722), dim3(256), 0, stream>>>(Wa, WAT);

    // v_g branch
    k_ag<<<dim3(B_), dim3(256), 0, stream>>>(sem, sem_table, ag);
    k_vg<<<dim3(B_ / 16), dim3(256), 0, stream>>>(ag, WbT, bbv, out);

    // factored input GEMMs: P1 (word part) + P2' (sememe part + bias)
    k_p<<<dim3(26, 19), dim3(256), 0, stream>>>(
        word, word_table, sem_table, WcatP,
        bih_f, bhh_f, bih_b, bhh_b, P1, P2);

    // recurrence: batch x unit partitioned, asm-pinned pipeline
    k_rec4<<<dim3(64, 2), dim3(512), 0, stream>>>(P1, P2, sem, WFf, WFb, hcat);

    // output projection (bf16 MFMA)
    k_out<<<dim3(M_ / 64), dim3(256), 0, stream>>>(hcat, WAT, ba, out);
}

// Round 7
// 532.983 us; speedup vs baseline: 1.6303x; 1.6091x over previous
//
#include <hip/hip_runtime.h>
#include <hip/hip_cooperative_groups.h>
#include <cstddef>
#include <cstdint>
#include <math.h>

#define B_   1024
#define L_   18
#define E_   300
#define H_   300
#define M_   (B_*L_)     // 18432 rows (b,l)
#define G4_  (4*H_)      // 1200
#define K2E_ (2*E_)      // 600

#define NPAD 2432        // gate-interleaved cols, both dirs (2*1216)
#define PSTR 2432        // P1/P2 row stride (fp32)
#define M2P  2304        // P2 padded rows (2186 valid)

// workspace layout (float offsets) -- r0 layout + sync counters
#define OFF_P1   ((size_t)0)                         // fp32 1024x2432
#define OFF_P2   (OFF_P1 + (size_t)1024*PSTR)        // fp32 2304x2432 (+bias)
#define OFF_HCAT (OFF_P2 + (size_t)M2P*PSTR)         // bf16 18432x608
#define OFF_AG   (OFF_HCAT + (size_t)M_*608/2)
#define OFF_WBT  (OFF_AG  + (size_t)B_*E_)
#define OFF_WFF  (OFF_WBT + 90000)                   // bf16 76x10x512 B-frag
#define OFF_WFB  (OFF_WFF + 194560)
#define OFF_WAT  (OFF_WFB + 194560)                  // bf16 19x19x512 B-frag
#define OFF_WCP  (OFF_WAT + 92416)                   // bf16 2x2432x320
#define OFF_HP   (OFF_WCP + 778240)                  // bf16 4x(64rt x 10kt x 512)
#define OFF_C    (OFF_HP + 655360)                   // fp32 2x1024x304 (fallback)
#define OFF_SYNC (OFF_C + (size_t)2*1024*304)        // int32 x16 group counters

#define HPSTR 327680      // shorts per hprev buffer

#define VOFF ((size_t)M_*H_)  // v_g offset in d_out

typedef short bf16x8 __attribute__((ext_vector_type(8)));
typedef float f32x4  __attribute__((ext_vector_type(4)));

__device__ __forceinline__ short f2bf(float f) {
    union { float f; uint32_t u; } c; c.f = f;
    uint32_t u = c.u + 0x7fffu + ((c.u >> 16) & 1u);   // RNE
    return (short)(u >> 16);
}

// ---------------------------------------------------------------------------
// WbT[k][o] = Wb[o*300 + k]; also zeroes the 16 group-barrier counters.
// ---------------------------------------------------------------------------
__global__ void k_prep(const float* __restrict__ Wb, float* __restrict__ WbT,
                       int* __restrict__ syncv)
{
    if (blockIdx.x == 0 && threadIdx.x < 32) syncv[threadIdx.x] = 0;
    int idx = blockIdx.x * 256 + threadIdx.x;
    if (idx < 90000) {
        int o = idx % 300;
        int k = idx / 300;
        WbT[idx] = Wb[o * 300 + k];
    }
}

// ---------------------------------------------------------------------------
// WcatP[p][n'][kp] bf16: p=0 -> Wih[:, kp], p=1 -> Wih[:, 300+kp].
// n' gate-interleaved: n'<1216 fwd (n'=4u+g -> row g*300+u), else bwd.
// ---------------------------------------------------------------------------
__global__ __launch_bounds__(256) void k_prep_wcp(const float* __restrict__ Wih_f,
                                                  const float* __restrict__ Wih_b,
                                                  short* __restrict__ WcatP)
{
    int idx = blockIdx.x * 256 + threadIdx.x;   // < 2*2432*320
    if (idx >= 2 * NPAD * 320) return;
    int p = idx / (NPAD * 320);
    int rem = idx - p * (NPAD * 320);
    int n = rem / 320;
    int kp = rem - n * 320;
    int fwd = (n < 1216);
    int nn = fwd ? n : n - 1216;
    float v = 0.f;
    if (kp < 300 && nn < G4_) {
        int u = nn >> 2, g = nn & 3;
        const float* W = fwd ? Wih_f : Wih_b;
        v = W[(size_t)(g * 300 + u) * K2E_ + (p ? 300 + kp : kp)];
    }
    WcatP[idx] = f2bf(v);
}

// ---------------------------------------------------------------------------
// Whh B-fragment pack: WF[d][(nt*10+kt)*512 + lane*8 + j] =
//   bf16(Whh_d[(g*300+u)*300 + k]),  n = nt*16+(lane&15) = 4u+g,
//   k = kt*32 + (lane>>4)*8 + j; zero pads.
// ---------------------------------------------------------------------------
__global__ __launch_bounds__(256) void k_prep_whh(const float* __restrict__ Whh_f,
                                                  const float* __restrict__ Whh_b,
                                                  short* __restrict__ WFf,
                                                  short* __restrict__ WFb)
{
    int idx = blockIdx.x * 256 + threadIdx.x;   // < 389120
    if (idx >= 389120) return;
    int d = blockIdx.y;
    int chunk = idx >> 9;           // nt*10+kt
    int rem   = idx & 511;
    int lane  = rem >> 3;
    int j     = rem & 7;
    int nt = chunk / 10, kt = chunk - nt * 10;
    int n = nt * 16 + (lane & 15);
    int k = kt * 32 + (lane >> 4) * 8 + j;
    float v = 0.f;
    if (n < G4_ && k < H_) {
        int u = n >> 2, g = n & 3;
        const float* W = d ? Whh_b : Whh_f;
        v = W[(size_t)(g * 300 + u) * H_ + k];
    }
    (d ? WFb : WFf)[idx] = f2bf(v);
}

// ---------------------------------------------------------------------------
// Wa B-fragment pack for k_out: N=304 (19 nt), K=608 (19 kt).
// ---------------------------------------------------------------------------
__global__ __launch_bounds__(256) void k_prep_wa(const float* __restrict__ Wa,
                                                 short* __restrict__ WAT)
{
    int idx = blockIdx.x * 256 + threadIdx.x;   // < 184832
    if (idx >= 184832) return;
    int chunk = idx >> 9;           // nt*19+kt
    int rem   = idx & 511;
    int lane  = rem >> 3;
    int j     = rem & 7;
    int nt = chunk / 19, kt = chunk - nt * 19;
    int o  = nt * 16 + (lane & 15);
    int kp = kt * 32 + (lane >> 4) * 8 + j;
    float v = 0.f;
    if (o < H_) {
        int k = -1;
        if (kp < 300)                   k = kp;
        else if (kp >= 304 && kp < 604) k = kp - 4;
        if (k >= 0) v = Wa[(size_t)o * K2E_ + k];
    }
    WAT[idx] = f2bf(v);
}

// ---------------------------------------------------------------------------
// a_g[b][e] = mean_l sem_table[sememes[b][l]][e]
// ---------------------------------------------------------------------------
__global__ __launch_bounds__(256) void k_ag(const int* __restrict__ sem,
                                            const float* __restrict__ sem_table,
                                            float* __restrict__ ag)
{
    int b = blockIdx.x;
    __shared__ int sm[L_];
    if (threadIdx.x < L_) sm[threadIdx.x] = sem[b * L_ + threadIdx.x];
    __syncthreads();
    for (int e = threadIdx.x; e < E_; e += 256) {
        float s = 0.f;
        #pragma unroll
        for (int l = 0; l < L_; ++l) s += sem_table[sm[l] * E_ + e];
        ag[(size_t)b * E_ + e] = s * (1.0f / (float)L_);
    }
}

// ---------------------------------------------------------------------------
// v_g = relu(a_g @ Wb^T + bb) -> d_out[VOFF + ...]
// ---------------------------------------------------------------------------
__global__ __launch_bounds__(256) void k_vg(const float* __restrict__ ag,
                                            const float* __restrict__ WbT,
                                            const float* __restrict__ bbv,
                                            float* __restrict__ out)
{
    int b0 = blockIdx.x * 16;
    __shared__ __align__(16) float ag_s[16 * E_];
    for (int idx = threadIdx.x; idx < 16 * E_; idx += 256)
        ag_s[idx] = ag[(size_t)b0 * E_ + idx];
    __syncthreads();
    for (int o = threadIdx.x; o < E_; o += 256) {
        float acc[16];
        #pragma unroll
        for (int i = 0; i < 16; ++i) acc[i] = 0.f;
        for (int k = 0; k < E_; ++k) {
            float w = WbT[k * E_ + o];
            #pragma unroll
            for (int i = 0; i < 16; ++i)
                acc[i] = fmaf(w, ag_s[i * E_ + k], acc[i]);
        }
        float bias = bbv[o];
        #pragma unroll
        for (int i = 0; i < 16; ++i) {
            float v = acc[i] + bias;
            out[VOFF + (size_t)(b0 + i) * E_ + o] = v > 0.f ? v : 0.f;
        }
    }
}

// ---------------------------------------------------------------------------
// k_p: P1 = w @ Wih1^T  (rows 0..1023, mb 0..7)
//      P2' = sem_table @ Wih2^T + bias  (rows 0..2303, mb 8..25)
// bf16 MFMA, 128x128 tiles, K=320 (300 valid). Grid (26, 19).
// ---------------------------------------------------------------------------
#define LDT 40

__global__ __launch_bounds__(256) void k_p(const int* __restrict__ word,
                                           const float* __restrict__ word_table,
                                           const float* __restrict__ sem_table,
                                           const short* __restrict__ WcatP,
                                           const float* __restrict__ bih_f,
                                           const float* __restrict__ bhh_f,
                                           const float* __restrict__ bih_b,
                                           const float* __restrict__ bhh_b,
                                           float* __restrict__ P1,
                                           float* __restrict__ P2)
{
    __shared__ __align__(16) short As[128 * LDT];
    __shared__ __align__(16) short Bs[128 * LDT];
    __shared__ const float* rowp[128];

    const int mb = blockIdx.x;
    const int p  = (mb >= 8);
    const int m0 = (p ? mb - 8 : mb) * 128;
    const int n0 = blockIdx.y * 128;
    const int tid = threadIdx.x;

    if (tid < 128) {
        int m = m0 + tid;
        rowp[tid] = p ? (m < 2186 ? sem_table + (size_t)m * E_ : (const float*)0)
                      : word_table + (size_t)word[m] * E_;
    }
    __syncthreads();

    f32x4 acc[4][4];
    #pragma unroll
    for (int i = 0; i < 4; ++i)
        #pragma unroll
        for (int j = 0; j < 4; ++j)
            acc[i][j] = (f32x4){0.f, 0.f, 0.f, 0.f};

    const int wv   = tid >> 6;
    const int lane = tid & 63;
    const int wm   = (wv >> 1) * 64;
    const int wn   = (wv & 1) * 64;
    const int lm   = lane & 15;
    const int quad = lane >> 4;

    const int r  = tid >> 1;
    const int kh = (tid & 1) * 16;
    const float* rp = rowp[r];
    const short* bsrc = WcatP + (size_t)p * (NPAD * 320) + (size_t)(n0 + r) * 320;

    for (int k0 = 0; k0 < 320; k0 += 32) {
        {
            const int kbase = k0 + kh;
            #pragma unroll
            for (int q = 0; q < 4; ++q) {
                int k = kbase + q * 4;
                float4 v = (k < E_ && rp) ? *(const float4*)&rp[k]
                                          : make_float4(0.f, 0.f, 0.f, 0.f);
                short4 s4;
                s4.x = f2bf(v.x); s4.y = f2bf(v.y);
                s4.z = f2bf(v.z); s4.w = f2bf(v.w);
                *(short4*)&As[r * LDT + kh + q * 4] = s4;
            }
        }
        {
            const short* src = bsrc + k0 + kh;
            *(int4*)&Bs[r * LDT + kh + 0] = *(const int4*)&src[0];
            *(int4*)&Bs[r * LDT + kh + 8] = *(const int4*)&src[8];
        }
        __syncthreads();

        bf16x8 af[4], bfr[4];
        #pragma unroll
        for (int i = 0; i < 4; ++i)
            af[i] = *(const bf16x8*)&As[(wm + 16 * i + lm) * LDT + quad * 8];
        #pragma unroll
        for (int j = 0; j < 4; ++j)
            bfr[j] = *(const bf16x8*)&Bs[(wn + 16 * j + lm) * LDT + quad * 8];
        #pragma unroll
        for (int i = 0; i < 4; ++i)
            #pragma unroll
            for (int j = 0; j < 4; ++j)
                acc[i][j] = __builtin_amdgcn_mfma_f32_16x16x32_bf16(
                    af[i], bfr[j], acc[i][j], 0, 0, 0);
        __syncthreads();
    }

    float* dst = p ? P2 : P1;
    #pragma unroll
    for (int j = 0; j < 4; ++j) {
        int n = n0 + wn + 16 * j + lm;
        float bias = 0.f;
        if (p) {
            int fwd = (n < 1216);
            int cc = fwd ? n : n - 1216;
            if (cc < G4_) {
                int u = cc >> 2, g = cc & 3;
                bias = fwd ? (bih_f[g * 300 + u] + bhh_f[g * 300 + u])
                           : (bih_b[g * 300 + u] + bhh_b[g * 300 + u]);
            }
        }
        #pragma unroll
        for (int i = 0; i < 4; ++i) {
            int mb2 = m0 + wm + 16 * i + quad * 4;
            #pragma unroll
            for (int reg = 0; reg < 4; ++reg)
                dst[(size_t)(mb2 + reg) * PSTR + n] = acc[i][j][reg] + bias;
        }
    }
}

// ---------------------------------------------------------------------------
// k_rec2: ALL 18 recurrence steps, persistent cooperative kernel (r0 proven
// structure: VGPR 88, no spills, resident Whh frags, ~12us/step wall).
//
// CHANGE vs r0: gg.sync() (global 304-block barrier) replaced by a
// fine-grained GROUP barrier. Block (mb,nb,d) reads h only for rows
// rt0..rt0+128 (its mb), produced exclusively by the 19 blocks (mb,*,d).
// -> 16 independent groups of 19 blocks, monotone counter per group
// (target 19*(s+1), zeroed by k_prep each launch). Groups drift freely;
// no global coupling. Release: per-thread __threadfence before arrival.
// Acquire: __threadfence after spin. Cooperative launch retained ONLY for
// the co-residency guarantee (304 <= 2/CU x 256). Last step: no barrier
// (stream ordering covers k_out).
// ---------------------------------------------------------------------------
__global__ __launch_bounds__(256, 2) void k_rec2(const float* __restrict__ P1,
                                                 const float* __restrict__ P2,
                                                 const int* __restrict__ sem,
                                                 const short* __restrict__ WFf,
                                                 const short* __restrict__ WFb,
                                                 short* __restrict__ hp,
                                                 short* __restrict__ hcat,
                                                 int* __restrict__ syncv)
{
    const int d  = blockIdx.z;
    const short* WF = d ? WFb : WFf;
    short* hc = hcat + (d ? 304 : 0);
    const int rt0 = blockIdx.x * 8;       // 8 row-tiles = 128 batch rows
    const int nb  = blockIdx.y;           // units nb*16..+15
    const int g   = d * 8 + blockIdx.x;   // sync group (16 groups x 19 blocks)
    const int tid  = threadIdx.x;
    const int lane = tid & 63;
    const int wv   = tid >> 6;
    const int quad = lane >> 4;

    __shared__ __align__(16) float Cs[128][68];   // 34.8 KB

    // resident Whh B-fragments for (nb, wv, d): 10 x bf16x8 = 40 VGPRs
    bf16x8 bfr[10];
    {
        const short* wp = WF + ((size_t)(nb * 4 + wv) * 10) * 512 + lane * 8;
        #pragma unroll
        for (int kt = 0; kt < 10; ++kt)
            bfr[kt] = *(const bf16x8*)(wp + kt * 512);
    }

    // epilogue thread roles: 128 rows x 2 unit-halves (8 units/thread)
    const int m  = tid >> 1;              // 0..127
    const int q  = tid & 1;
    const int b  = rt0 * 16 + m;
    const int u0 = nb * 16 + 8 * q;
    const bool a0 = (u0 < H_);
    const bool a1 = (u0 + 4 < H_);
    const size_t pcol = (size_t)d * 1216 + 4 * u0;
    const float* p1r = P1 + (size_t)b * PSTR + pcol;
    float c8[8] = {0.f,0.f,0.f,0.f,0.f,0.f,0.f,0.f};

    // hp fragment-layout offset (u0 and u0+4 chunks are hofs and hofs+4)
    size_t hofs;
    {
        int rt = b >> 4, ktu = u0 >> 5;
        int fl = (b & 15) | (((u0 >> 3) & 3) << 4);
        hofs = ((size_t)(rt * 10 + ktu) * 512) + (size_t)fl * 8 + (u0 & 7);
    }

    for (int s = 0; s < L_; ++s) {
        const int t = d ? (L_ - 1 - s) : s;
        const short* hin = hp + (size_t)(d * 2 + ((s + 1) & 1)) * HPSTR;
        short*      hout = hp + (size_t)(d * 2 + (s & 1)) * HPSTR;

        // ---- gather x-part early (independent of recurrence GEMM) ----
        float4 xv[8];
        {
            const int svt = sem[b * L_ + t];
            const float* p2r = P2 + (size_t)svt * PSTR + pcol;
            #pragma unroll
            for (int i = 0; i < 8; ++i) xv[i] = *(const float4*)&p2r[4 * i];
            if (svt != 0) {
                #pragma unroll
                for (int i = 0; i < 8; ++i) {
                    float4 a = *(const float4*)&p1r[4 * i];
                    xv[i].x += a.x; xv[i].y += a.y; xv[i].z += a.z; xv[i].w += a.w;
                }
            }
        }

        // ---- gates = h_prev @ Whh^T (MFMA) ----
        f32x4 acc[8];
        #pragma unroll
        for (int mt = 0; mt < 8; ++mt) acc[mt] = (f32x4){0.f, 0.f, 0.f, 0.f};
        if (s > 0) {
            #pragma unroll
            for (int kt = 0; kt < 10; ++kt) {
                #pragma unroll
                for (int mt = 0; mt < 8; ++mt) {
                    bf16x8 af = *(const bf16x8*)&hin[((size_t)(rt0 + mt) * 10 + kt) * 512 + lane * 8];
                    acc[mt] = __builtin_amdgcn_mfma_f32_16x16x32_bf16(af, bfr[kt], acc[mt], 0, 0, 0);
                }
            }
        }

        // ---- C tile -> LDS (wave wv owns cols wv*16..+15) ----
        #pragma unroll
        for (int mt = 0; mt < 8; ++mt)
            #pragma unroll
            for (int r = 0; r < 4; ++r)
                Cs[mt * 16 + quad * 4 + r][wv * 16 + (lane & 15)] = acc[mt][r];
        __syncthreads();

        // ---- fused LSTM cell (8 units/thread) ----
        {
            short hn[8];
            #pragma unroll
            for (int i = 0; i < 8; ++i) {
                float4 gv = *(const float4*)&Cs[m][32 * q + 4 * i];
                float gi = xv[i].x + gv.x;
                float gf = xv[i].y + gv.y;
                float gg2 = xv[i].z + gv.z;
                float go = xv[i].w + gv.w;
                float iv = 1.f / (1.f + __expf(-gi));
                float fv = 1.f / (1.f + __expf(-gf));
                float tg = 1.f - 2.f / (__expf(2.f * gg2) + 1.f);
                float ov = 1.f / (1.f + __expf(-go));
                float cc = fmaf(fv, c8[i], iv * tg);
                c8[i] = cc;
                float th = 1.f - 2.f / (__expf(2.f * cc) + 1.f);
                hn[i] = f2bf(ov * th);
            }
            if (a0) {
                short4 h4 = {hn[0], hn[1], hn[2], hn[3]};
                *(short4*)&hout[hofs] = h4;
                *(short4*)&hc[((size_t)b * L_ + t) * 608 + u0] = h4;
            }
            if (a1) {
                short4 h4 = {hn[4], hn[5], hn[6], hn[7]};
                *(short4*)&hout[hofs + 4] = h4;
                *(short4*)&hc[((size_t)b * L_ + t) * 608 + u0 + 4] = h4;
            }
        }

        // ---- group barrier: 19 blocks (mb,*,d); skip after last step ----
        if (s < L_ - 1) {
            __threadfence();          // release: drain this thread's h stores
            __syncthreads();          // all threads' fences complete
            if (tid == 0) {
                __hip_atomic_fetch_add(&syncv[g], 1, __ATOMIC_RELEASE,
                                       __HIP_MEMORY_SCOPE_AGENT);
                const int tgt = 19 * (s + 1);
                while (__hip_atomic_load(&syncv[g], __ATOMIC_ACQUIRE,
                                         __HIP_MEMORY_SCOPE_AGENT) < tgt)
                    __builtin_amdgcn_s_sleep(2);
            }
            __syncthreads();          // also the intra-block barrier for Cs reuse
            __threadfence();          // acquire: invalidate stale caches
        }
    }
}

// ---------------------------------------------------------------------------
// k_step2 (fallback path): ONE recurrence step, both dirs.
// Grid (16 mb, 19 nb, 2 d), 256 thr. Identical arithmetic to k_rec2.
// ---------------------------------------------------------------------------
__global__ __launch_bounds__(256) void k_step2(const float* __restrict__ P1,
                                               const float* __restrict__ P2,
                                               const int* __restrict__ sem,
                                               const short* __restrict__ WFf,
                                               const short* __restrict__ WFb,
                                               short* __restrict__ hp,
                                               float* __restrict__ cbuf,
                                               short* __restrict__ hcat,
                                               int s)
{
    const int d  = blockIdx.z;
    const short* WF = d ? WFb : WFf;
    const int t = d ? (L_ - 1 - s) : s;
    const short* hin = hp + (size_t)(d * 2 + ((s + 1) & 1)) * HPSTR;
    short*      hout = hp + (size_t)(d * 2 + (s & 1)) * HPSTR;
    short* hc = hcat + (d ? 304 : 0);
    float* cp = cbuf + (size_t)d * (1024 * 304);

    const int m0 = blockIdx.x * 64;
    const int rt0 = blockIdx.x * 4;
    const int nb = blockIdx.y;
    const int tid  = threadIdx.x;
    const int lane = tid & 63;
    const int wv   = tid >> 6;
    const int quad = lane >> 4;

    __shared__ __align__(16) float Cs[64][68];

    f32x4 acc[4];
    #pragma unroll
    for (int mt = 0; mt < 4; ++mt) acc[mt] = (f32x4){0.f, 0.f, 0.f, 0.f};

    if (s > 0) {
        const short* wp = WF + ((size_t)(nb * 4 + wv) * 10) * 512 + lane * 8;
        #pragma unroll
        for (int kt = 0; kt < 10; ++kt) {
            bf16x8 bf = *(const bf16x8*)(wp + kt * 512);
            #pragma unroll
            for (int mt = 0; mt < 4; ++mt) {
                bf16x8 af = *(const bf16x8*)&hin[((size_t)(rt0 + mt) * 10 + kt) * 512 + lane * 8];
                acc[mt] = __builtin_amdgcn_mfma_f32_16x16x32_bf16(af, bf, acc[mt], 0, 0, 0);
            }
        }
    }

    #pragma unroll
    for (int mt = 0; mt < 4; ++mt)
        #pragma unroll
        for (int r = 0; r < 4; ++r)
            Cs[mt * 16 + quad * 4 + r][wv * 16 + (lane & 15)] = acc[mt][r];
    __syncthreads();

    const int m = tid >> 2;
    const int q = tid & 3;
    const int b = m0 + m;
    const int u0 = nb * 16 + 4 * q;
    if (u0 < H_) {
        const int svt = sem[b * L_ + t];
        const size_t pcol = (size_t)d * 1216 + 4 * u0;
        const float* p2r = P2 + (size_t)svt * PSTR + pcol;
        const float* p1r = P1 + (size_t)b * PSTR + pcol;
        float4 xv[4];
        #pragma unroll
        for (int i = 0; i < 4; ++i) xv[i] = *(const float4*)&p2r[4 * i];
        if (svt != 0) {
            #pragma unroll
            for (int i = 0; i < 4; ++i) {
                float4 a = *(const float4*)&p1r[4 * i];
                xv[i].x += a.x; xv[i].y += a.y; xv[i].z += a.z; xv[i].w += a.w;
            }
        }
        float4 cpv = (s > 0) ? *(const float4*)&cp[(size_t)b * 304 + u0]
                             : make_float4(0.f, 0.f, 0.f, 0.f);
        float cold[4] = {cpv.x, cpv.y, cpv.z, cpv.w};
        float cnew[4];
        short hn[4];
        #pragma unroll
        for (int i = 0; i < 4; ++i) {
            float4 gv = *(const float4*)&Cs[m][16 * q + 4 * i];
            float gi = xv[i].x + gv.x;
            float gf = xv[i].y + gv.y;
            float gg = xv[i].z + gv.z;
            float go = xv[i].w + gv.w;
            float iv = 1.f / (1.f + __expf(-gi));
            float fv = 1.f / (1.f + __expf(-gf));
            float tg = 1.f - 2.f / (__expf(2.f * gg) + 1.f);
            float ov = 1.f / (1.f + __expf(-go));
            float cc = fmaf(fv, cold[i], iv * tg);
            cnew[i] = cc;
            float th = 1.f - 2.f / (__expf(2.f * cc) + 1.f);
            hn[i] = f2bf(ov * th);
        }
        *(float4*)&cp[(size_t)b * 304 + u0] = make_float4(cnew[0], cnew[1], cnew[2], cnew[3]);
        short4 h4 = {hn[0], hn[1], hn[2], hn[3]};
        {
            int rt = b >> 4, ktu = u0 >> 5;
            int fl = (b & 15) | (((u0 >> 3) & 3) << 4);
            *(short4*)&hout[((size_t)(rt * 10 + ktu) * 512) + (size_t)fl * 8 + (u0 & 7)] = h4;
        }
        *(short4*)&hc[((size_t)b * L_ + t) * 608 + u0] = h4;
    }
}

// ---------------------------------------------------------------------------
// k_out: V = relu(hcat @ WAT^T + ba)  bf16 MFMA.  M=18432, N=304(300), K=608.
// ---------------------------------------------------------------------------
__global__ __launch_bounds__(256) void k_out(const short* __restrict__ hcat,
                                             const short* __restrict__ WAT,
                                             const float* __restrict__ ba,
                                             float* __restrict__ out)
{
    const int m0 = blockIdx.x * 64;
    const int tid = threadIdx.x;
    const int lane = tid & 63;
    const int wv = tid >> 6;
    const int lm = lane & 15;
    const int quad = lane >> 4;

    __shared__ __align__(16) short A_s[64][616];

    for (int idx = tid; idx < 4864; idx += 256) {   // 64 rows * 76 chunks
        int r = idx / 76, c8 = idx - r * 76;
        *(int4*)&A_s[r][c8 * 8] = *(const int4*)&hcat[(size_t)(m0 + r) * 608 + c8 * 8];
    }
    __syncthreads();

    f32x4 acc[4][5];
    #pragma unroll
    for (int mt = 0; mt < 4; ++mt)
        #pragma unroll
        for (int q = 0; q < 5; ++q)
            acc[mt][q] = (f32x4){0.f, 0.f, 0.f, 0.f};

    for (int kt = 0; kt < 19; ++kt) {
        bf16x8 af[4];
        #pragma unroll
        for (int mt = 0; mt < 4; ++mt)
            af[mt] = *(const bf16x8*)&A_s[mt * 16 + lm][kt * 32 + quad * 8];
        #pragma unroll
        for (int q = 0; q < 5; ++q) {
            int nt = wv + 4 * q;
            if (nt < 19) {
                bf16x8 bf = *(const bf16x8*)&WAT[((size_t)(nt * 19 + kt) * 64 + lane) * 8];
                #pragma unroll
                for (int mt = 0; mt < 4; ++mt)
                    acc[mt][q] = __builtin_amdgcn_mfma_f32_16x16x32_bf16(
                        af[mt], bf, acc[mt][q], 0, 0, 0);
            }
        }
    }

    #pragma unroll
    for (int q = 0; q < 5; ++q) {
        int nt = wv + 4 * q;
        if (nt < 19) {
            int o = nt * 16 + lm;
            if (o < H_) {
                float bias = ba[o];
                #pragma unroll
                for (int mt = 0; mt < 4; ++mt) {
                    #pragma unroll
                    for (int r = 0; r < 4; ++r) {
                        int m = m0 + mt * 16 + quad * 4 + r;
                        float v = acc[mt][q][r] + bias;
                        out[(size_t)m * H_ + o] = v > 0.f ? v : 0.f;
                    }
                }
            }
        }
    }
}

// ---------------------------------------------------------------------------
extern "C" void kernel_launch(void* const* d_in, const int* in_sizes, int n_in,
                              void* d_out, int out_size, void* d_ws, size_t ws_size,
                              hipStream_t stream) {
    const int*   word       = (const int*)  d_in[0];
    const int*   sem        = (const int*)  d_in[1];
    const float* word_table = (const float*)d_in[2];
    const float* sem_table  = (const float*)d_in[3];
    const float* Wih_f      = (const float*)d_in[4];
    const float* Whh_f      = (const float*)d_in[5];
    const float* bih_f      = (const float*)d_in[6];
    const float* bhh_f      = (const float*)d_in[7];
    const float* Wih_b      = (const float*)d_in[8];
    const float* Whh_b      = (const float*)d_in[9];
    const float* bih_b      = (const float*)d_in[10];
    const float* bhh_b      = (const float*)d_in[11];
    const float* Wa         = (const float*)d_in[12];
    const float* ba         = (const float*)d_in[13];
    const float* Wb         = (const float*)d_in[14];
    const float* bbv        = (const float*)d_in[15];

    float* out = (float*)d_out;
    float* ws  = (float*)d_ws;

    float* P1    = ws + OFF_P1;
    float* P2    = ws + OFF_P2;
    short* hcat  = (short*)(ws + OFF_HCAT);
    float* ag    = ws + OFF_AG;
    float* WbT   = ws + OFF_WBT;
    short* WFf   = (short*)(ws + OFF_WFF);
    short* WFb   = (short*)(ws + OFF_WFB);
    short* WAT   = (short*)(ws + OFF_WAT);
    short* WcatP = (short*)(ws + OFF_WCP);
    short* hp    = (short*)(ws + OFF_HP);
    float* cbuf  = ws + OFF_C;
    int*   syncv = (int*)(ws + OFF_SYNC);

    // weight re-layouts (every call; inputs restored each launch)
    k_prep<<<dim3(352), dim3(256), 0, stream>>>(Wb, WbT, syncv);
    k_prep_wcp<<<dim3((2 * NPAD * 320 + 255) / 256), dim3(256), 0, stream>>>(
        Wih_f, Wih_b, WcatP);
    k_prep_whh<<<dim3(1520, 2), dim3(256), 0, stream>>>(Whh_f, Whh_b, WFf, WFb);
    k_prep_wa<<<dim3(722), dim3(256), 0, stream>>>(Wa, WAT);

    // v_g branch
    k_ag<<<dim3(B_), dim3(256), 0, stream>>>(sem, sem_table, ag);
    k_vg<<<dim3(B_ / 16), dim3(256), 0, stream>>>(ag, WbT, bbv, out);

    // factored input GEMMs: P1 (word part) + P2' (sememe part + bias)
    k_p<<<dim3(26, 19), dim3(256), 0, stream>>>(
        word, word_table, sem_table, WcatP,
        bih_f, bhh_f, bih_b, bhh_b, P1, P2);

    // recurrence: cooperative single-launch (co-residency guaranteed) with
    // fine-grained 19-block group barriers; proven 18-launch fallback else.
    int useCoop = 0;
    {
        int dev = 0, coopAttr = 0, numCU = 0, maxBlk = 0;
        (void)hipGetDevice(&dev);
        (void)hipDeviceGetAttribute(&coopAttr, hipDeviceAttributeCooperativeLaunch, dev);
        (void)hipDeviceGetAttribute(&numCU, hipDeviceAttributeMultiprocessorCount, dev);
        (void)hipOccupancyMaxActiveBlocksPerMultiprocessor(&maxBlk, k_rec2, 256, 0);
        if (coopAttr && (long)maxBlk * (long)numCU >= 304) useCoop = 1;
    }
    if (useCoop) {
        void* args[] = {(void*)&P1, (void*)&P2, (void*)&sem,
                        (void*)&WFf, (void*)&WFb, (void*)&hp, (void*)&hcat,
                        (void*)&syncv};
        hipError_t e = hipLaunchCooperativeKernel((const void*)k_rec2,
                                                  dim3(8, 19, 2), dim3(256),
                                                  args, 0, stream);
        if (e != hipSuccess) useCoop = 0;
    }
    if (!useCoop) {
        for (int s = 0; s < L_; ++s) {
            k_step2<<<dim3(16, 19, 2), dim3(256), 0, stream>>>(
                P1, P2, sem, WFf, WFb, hp, cbuf, hcat, s);
        }
    }

    // output projection (bf16 MFMA)
    k_out<<<dim3(M_ / 64), dim3(256), 0, stream>>>(hcat, WAT, ba, out);
}

// Round 8
// 532.767 us; speedup vs baseline: 1.6309x; 1.0004x over previous
//
#include <hip/hip_runtime.h>
#include <hip/hip_cooperative_groups.h>
#include <cstddef>
#include <cstdint>
#include <math.h>

#define B_   1024
#define L_   18
#define E_   300
#define H_   300
#define M_   (B_*L_)     // 18432 rows (b,l)
#define G4_  (4*H_)      // 1200
#define K2E_ (2*E_)      // 600

#define NPAD 2432        // gate-interleaved cols, both dirs (2*1216)
#define PSTR 2432        // P1/P2 row stride (fp32)
#define M2P  2304        // P2 padded rows (2186 valid)

// workspace layout (float offsets) -- r0 layout + padded sync counters
#define OFF_P1   ((size_t)0)                         // fp32 1024x2432
#define OFF_P2   (OFF_P1 + (size_t)1024*PSTR)        // fp32 2304x2432 (+bias)
#define OFF_HCAT (OFF_P2 + (size_t)M2P*PSTR)         // bf16 18432x608
#define OFF_AG   (OFF_HCAT + (size_t)M_*608/2)
#define OFF_WBT  (OFF_AG  + (size_t)B_*E_)
#define OFF_WFF  (OFF_WBT + 90000)                   // bf16 76x10x512 B-frag
#define OFF_WFB  (OFF_WFF + 194560)
#define OFF_WAT  (OFF_WFB + 194560)                  // bf16 19x19x512 B-frag
#define OFF_WCP  (OFF_WAT + 92416)                   // bf16 2x2432x320
#define OFF_HP   (OFF_WCP + 778240)                  // bf16 4x(64rt x 10kt x 512)
#define OFF_C    (OFF_HP + 655360)                   // fp32 2x1024x304 (fallback)
#define OFF_SYNC (OFF_C + (size_t)2*1024*304)        // int32 x16 groups, 256B stride

#define HPSTR 327680      // shorts per hprev buffer

#define VOFF ((size_t)M_*H_)  // v_g offset in d_out

typedef short bf16x8 __attribute__((ext_vector_type(8)));
typedef float f32x4  __attribute__((ext_vector_type(4)));

__device__ __forceinline__ short f2bf(float f) {
    union { float f; uint32_t u; } c; c.f = f;
    uint32_t u = c.u + 0x7fffu + ((c.u >> 16) & 1u);   // RNE
    return (short)(u >> 16);
}

// ---------------------------------------------------------------------------
// WbT[k][o] = Wb[o*300 + k]; also zeroes the padded group-barrier counters.
// ---------------------------------------------------------------------------
__global__ void k_prep(const float* __restrict__ Wb, float* __restrict__ WbT,
                       int* __restrict__ syncv)
{
    int idx = blockIdx.x * 256 + threadIdx.x;
    if (idx < 1024) syncv[idx] = 0;          // 16 groups x 64-int (256B) stride
    if (idx < 90000) {
        int o = idx % 300;
        int k = idx / 300;
        WbT[idx] = Wb[o * 300 + k];
    }
}

// ---------------------------------------------------------------------------
// WcatP[p][n'][kp] bf16: p=0 -> Wih[:, kp], p=1 -> Wih[:, 300+kp].
// n' gate-interleaved: n'<1216 fwd (n'=4u+g -> row g*300+u), else bwd.
// ---------------------------------------------------------------------------
__global__ __launch_bounds__(256) void k_prep_wcp(const float* __restrict__ Wih_f,
                                                  const float* __restrict__ Wih_b,
                                                  short* __restrict__ WcatP)
{
    int idx = blockIdx.x * 256 + threadIdx.x;   // < 2*2432*320
    if (idx >= 2 * NPAD * 320) return;
    int p = idx / (NPAD * 320);
    int rem = idx - p * (NPAD * 320);
    int n = rem / 320;
    int kp = rem - n * 320;
    int fwd = (n < 1216);
    int nn = fwd ? n : n - 1216;
    float v = 0.f;
    if (kp < 300 && nn < G4_) {
        int u = nn >> 2, g = nn & 3;
        const float* W = fwd ? Wih_f : Wih_b;
        v = W[(size_t)(g * 300 + u) * K2E_ + (p ? 300 + kp : kp)];
    }
    WcatP[idx] = f2bf(v);
}

// ---------------------------------------------------------------------------
// Whh B-fragment pack: WF[d][(nt*10+kt)*512 + lane*8 + j] =
//   bf16(Whh_d[(g*300+u)*300 + k]),  n = nt*16+(lane&15) = 4u+g,
//   k = kt*32 + (lane>>4)*8 + j; zero pads.
// ---------------------------------------------------------------------------
__global__ __launch_bounds__(256) void k_prep_whh(const float* __restrict__ Whh_f,
                                                  const float* __restrict__ Whh_b,
                                                  short* __restrict__ WFf,
                                                  short* __restrict__ WFb)
{
    int idx = blockIdx.x * 256 + threadIdx.x;   // < 389120
    if (idx >= 389120) return;
    int d = blockIdx.y;
    int chunk = idx >> 9;           // nt*10+kt
    int rem   = idx & 511;
    int lane  = rem >> 3;
    int j     = rem & 7;
    int nt = chunk / 10, kt = chunk - nt * 10;
    int n = nt * 16 + (lane & 15);
    int k = kt * 32 + (lane >> 4) * 8 + j;
    float v = 0.f;
    if (n < G4_ && k < H_) {
        int u = n >> 2, g = n & 3;
        const float* W = d ? Whh_b : Whh_f;
        v = W[(size_t)(g * 300 + u) * H_ + k];
    }
    (d ? WFb : WFf)[idx] = f2bf(v);
}

// ---------------------------------------------------------------------------
// Wa B-fragment pack for k_out: N=304 (19 nt), K=608 (19 kt).
// ---------------------------------------------------------------------------
__global__ __launch_bounds__(256) void k_prep_wa(const float* __restrict__ Wa,
                                                 short* __restrict__ WAT)
{
    int idx = blockIdx.x * 256 + threadIdx.x;   // < 184832
    if (idx >= 184832) return;
    int chunk = idx >> 9;           // nt*19+kt
    int rem   = idx & 511;
    int lane  = rem >> 3;
    int j     = rem & 7;
    int nt = chunk / 19, kt = chunk - nt * 19;
    int o  = nt * 16 + (lane & 15);
    int kp = kt * 32 + (lane >> 4) * 8 + j;
    float v = 0.f;
    if (o < H_) {
        int k = -1;
        if (kp < 300)                   k = kp;
        else if (kp >= 304 && kp < 604) k = kp - 4;
        if (k >= 0) v = Wa[(size_t)o * K2E_ + k];
    }
    WAT[idx] = f2bf(v);
}

// ---------------------------------------------------------------------------
// a_g[b][e] = mean_l sem_table[sememes[b][l]][e]
// ---------------------------------------------------------------------------
__global__ __launch_bounds__(256) void k_ag(const int* __restrict__ sem,
                                            const float* __restrict__ sem_table,
                                            float* __restrict__ ag)
{
    int b = blockIdx.x;
    __shared__ int sm[L_];
    if (threadIdx.x < L_) sm[threadIdx.x] = sem[b * L_ + threadIdx.x];
    __syncthreads();
    for (int e = threadIdx.x; e < E_; e += 256) {
        float s = 0.f;
        #pragma unroll
        for (int l = 0; l < L_; ++l) s += sem_table[sm[l] * E_ + e];
        ag[(size_t)b * E_ + e] = s * (1.0f / (float)L_);
    }
}

// ---------------------------------------------------------------------------
// v_g = relu(a_g @ Wb^T + bb) -> d_out[VOFF + ...]
// ---------------------------------------------------------------------------
__global__ __launch_bounds__(256) void k_vg(const float* __restrict__ ag,
                                            const float* __restrict__ WbT,
                                            const float* __restrict__ bbv,
                                            float* __restrict__ out)
{
    int b0 = blockIdx.x * 16;
    __shared__ __align__(16) float ag_s[16 * E_];
    for (int idx = threadIdx.x; idx < 16 * E_; idx += 256)
        ag_s[idx] = ag[(size_t)b0 * E_ + idx];
    __syncthreads();
    for (int o = threadIdx.x; o < E_; o += 256) {
        float acc[16];
        #pragma unroll
        for (int i = 0; i < 16; ++i) acc[i] = 0.f;
        for (int k = 0; k < E_; ++k) {
            float w = WbT[k * E_ + o];
            #pragma unroll
            for (int i = 0; i < 16; ++i)
                acc[i] = fmaf(w, ag_s[i * E_ + k], acc[i]);
        }
        float bias = bbv[o];
        #pragma unroll
        for (int i = 0; i < 16; ++i) {
            float v = acc[i] + bias;
            out[VOFF + (size_t)(b0 + i) * E_ + o] = v > 0.f ? v : 0.f;
        }
    }
}

// ---------------------------------------------------------------------------
// k_p: P1 = w @ Wih1^T  (rows 0..1023, mb 0..7)
//      P2' = sem_table @ Wih2^T + bias  (rows 0..2303, mb 8..25)
// bf16 MFMA, 128x128 tiles, K=320 (300 valid). Grid (26, 19).
// ---------------------------------------------------------------------------
#define LDT 40

__global__ __launch_bounds__(256) void k_p(const int* __restrict__ word,
                                           const float* __restrict__ word_table,
                                           const float* __restrict__ sem_table,
                                           const short* __restrict__ WcatP,
                                           const float* __restrict__ bih_f,
                                           const float* __restrict__ bhh_f,
                                           const float* __restrict__ bih_b,
                                           const float* __restrict__ bhh_b,
                                           float* __restrict__ P1,
                                           float* __restrict__ P2)
{
    __shared__ __align__(16) short As[128 * LDT];
    __shared__ __align__(16) short Bs[128 * LDT];
    __shared__ const float* rowp[128];

    const int mb = blockIdx.x;
    const int p  = (mb >= 8);
    const int m0 = (p ? mb - 8 : mb) * 128;
    const int n0 = blockIdx.y * 128;
    const int tid = threadIdx.x;

    if (tid < 128) {
        int m = m0 + tid;
        rowp[tid] = p ? (m < 2186 ? sem_table + (size_t)m * E_ : (const float*)0)
                      : word_table + (size_t)word[m] * E_;
    }
    __syncthreads();

    f32x4 acc[4][4];
    #pragma unroll
    for (int i = 0; i < 4; ++i)
        #pragma unroll
        for (int j = 0; j < 4; ++j)
            acc[i][j] = (f32x4){0.f, 0.f, 0.f, 0.f};

    const int wv   = tid >> 6;
    const int lane = tid & 63;
    const int wm   = (wv >> 1) * 64;
    const int wn   = (wv & 1) * 64;
    const int lm   = lane & 15;
    const int quad = lane >> 4;

    const int r  = tid >> 1;
    const int kh = (tid & 1) * 16;
    const float* rp = rowp[r];
    const short* bsrc = WcatP + (size_t)p * (NPAD * 320) + (size_t)(n0 + r) * 320;

    for (int k0 = 0; k0 < 320; k0 += 32) {
        {
            const int kbase = k0 + kh;
            #pragma unroll
            for (int q = 0; q < 4; ++q) {
                int k = kbase + q * 4;
                float4 v = (k < E_ && rp) ? *(const float4*)&rp[k]
                                          : make_float4(0.f, 0.f, 0.f, 0.f);
                short4 s4;
                s4.x = f2bf(v.x); s4.y = f2bf(v.y);
                s4.z = f2bf(v.z); s4.w = f2bf(v.w);
                *(short4*)&As[r * LDT + kh + q * 4] = s4;
            }
        }
        {
            const short* src = bsrc + k0 + kh;
            *(int4*)&Bs[r * LDT + kh + 0] = *(const int4*)&src[0];
            *(int4*)&Bs[r * LDT + kh + 8] = *(const int4*)&src[8];
        }
        __syncthreads();

        bf16x8 af[4], bfr[4];
        #pragma unroll
        for (int i = 0; i < 4; ++i)
            af[i] = *(const bf16x8*)&As[(wm + 16 * i + lm) * LDT + quad * 8];
        #pragma unroll
        for (int j = 0; j < 4; ++j)
            bfr[j] = *(const bf16x8*)&Bs[(wn + 16 * j + lm) * LDT + quad * 8];
        #pragma unroll
        for (int i = 0; i < 4; ++i)
            #pragma unroll
            for (int j = 0; j < 4; ++j)
                acc[i][j] = __builtin_amdgcn_mfma_f32_16x16x32_bf16(
                    af[i], bfr[j], acc[i][j], 0, 0, 0);
        __syncthreads();
    }

    float* dst = p ? P2 : P1;
    #pragma unroll
    for (int j = 0; j < 4; ++j) {
        int n = n0 + wn + 16 * j + lm;
        float bias = 0.f;
        if (p) {
            int fwd = (n < 1216);
            int cc = fwd ? n : n - 1216;
            if (cc < G4_) {
                int u = cc >> 2, g = cc & 3;
                bias = fwd ? (bih_f[g * 300 + u] + bhh_f[g * 300 + u])
                           : (bih_b[g * 300 + u] + bhh_b[g * 300 + u]);
            }
        }
        #pragma unroll
        for (int i = 0; i < 4; ++i) {
            int mb2 = m0 + wm + 16 * i + quad * 4;
            #pragma unroll
            for (int reg = 0; reg < 4; ++reg)
                dst[(size_t)(mb2 + reg) * PSTR + n] = acc[i][j][reg] + bias;
        }
    }
}

// ---------------------------------------------------------------------------
// k_rec2: ALL 18 recurrence steps, persistent cooperative kernel (r0 proven
// structure: VGPR 88, no spills, resident Whh frags).
//
// r8 CHANGE (vs r7): the 16 group counters are PADDED to separate 256B
// lines (syncv[g<<6]). r0 (one cg counter) and r7 (16 counters in ONE 64B
// line) were wall-identical at ~12us/step: ~300 agents (arrival RMWs +
// ACQUIRE pollers) serialized on a single hot L3 line every step -- the
// group split changed logical coupling but not the physical line. Padding
// cuts per-line agents from ~300 to 19.
// Fence dedup: per-wave s_waitcnt drain (cheap) + ONE tid0
// __threadfence pair (buffer_wbl2/inv are per-XCD ops -- 4x redundant
// per-thread fences replaced; stores reach L2 by the drain, tid0's wbl2
// flushes them).
// ---------------------------------------------------------------------------
__global__ __launch_bounds__(256, 2) void k_rec2(const float* __restrict__ P1,
                                                 const float* __restrict__ P2,
                                                 const int* __restrict__ sem,
                                                 const short* __restrict__ WFf,
                                                 const short* __restrict__ WFb,
                                                 short* __restrict__ hp,
                                                 short* __restrict__ hcat,
                                                 int* __restrict__ syncv)
{
    const int d  = blockIdx.z;
    const short* WF = d ? WFb : WFf;
    short* hc = hcat + (d ? 304 : 0);
    const int rt0 = blockIdx.x * 8;       // 8 row-tiles = 128 batch rows
    const int nb  = blockIdx.y;           // units nb*16..+15
    const int g   = d * 8 + blockIdx.x;   // sync group (16 groups x 19 blocks)
    const int tid  = threadIdx.x;
    const int lane = tid & 63;
    const int wv   = tid >> 6;
    const int quad = lane >> 4;

    __shared__ __align__(16) float Cs[128][68];   // 34.8 KB

    // resident Whh B-fragments for (nb, wv, d): 10 x bf16x8 = 40 VGPRs
    bf16x8 bfr[10];
    {
        const short* wp = WF + ((size_t)(nb * 4 + wv) * 10) * 512 + lane * 8;
        #pragma unroll
        for (int kt = 0; kt < 10; ++kt)
            bfr[kt] = *(const bf16x8*)(wp + kt * 512);
    }

    // epilogue thread roles: 128 rows x 2 unit-halves (8 units/thread)
    const int m  = tid >> 1;              // 0..127
    const int q  = tid & 1;
    const int b  = rt0 * 16 + m;
    const int u0 = nb * 16 + 8 * q;
    const bool a0 = (u0 < H_);
    const bool a1 = (u0 + 4 < H_);
    const size_t pcol = (size_t)d * 1216 + 4 * u0;
    const float* p1r = P1 + (size_t)b * PSTR + pcol;
    float c8[8] = {0.f,0.f,0.f,0.f,0.f,0.f,0.f,0.f};

    // hp fragment-layout offset (u0 and u0+4 chunks are hofs and hofs+4)
    size_t hofs;
    {
        int rt = b >> 4, ktu = u0 >> 5;
        int fl = (b & 15) | (((u0 >> 3) & 3) << 4);
        hofs = ((size_t)(rt * 10 + ktu) * 512) + (size_t)fl * 8 + (u0 & 7);
    }

    for (int s = 0; s < L_; ++s) {
        const int t = d ? (L_ - 1 - s) : s;
        const short* hin = hp + (size_t)(d * 2 + ((s + 1) & 1)) * HPSTR;
        short*      hout = hp + (size_t)(d * 2 + (s & 1)) * HPSTR;

        // ---- gather x-part early (independent of recurrence GEMM) ----
        float4 xv[8];
        {
            const int svt = sem[b * L_ + t];
            const float* p2r = P2 + (size_t)svt * PSTR + pcol;
            #pragma unroll
            for (int i = 0; i < 8; ++i) xv[i] = *(const float4*)&p2r[4 * i];
            if (svt != 0) {
                #pragma unroll
                for (int i = 0; i < 8; ++i) {
                    float4 a = *(const float4*)&p1r[4 * i];
                    xv[i].x += a.x; xv[i].y += a.y; xv[i].z += a.z; xv[i].w += a.w;
                }
            }
        }

        // ---- gates = h_prev @ Whh^T (MFMA) ----
        f32x4 acc[8];
        #pragma unroll
        for (int mt = 0; mt < 8; ++mt) acc[mt] = (f32x4){0.f, 0.f, 0.f, 0.f};
        if (s > 0) {
            #pragma unroll
            for (int kt = 0; kt < 10; ++kt) {
                #pragma unroll
                for (int mt = 0; mt < 8; ++mt) {
                    bf16x8 af = *(const bf16x8*)&hin[((size_t)(rt0 + mt) * 10 + kt) * 512 + lane * 8];
                    acc[mt] = __builtin_amdgcn_mfma_f32_16x16x32_bf16(af, bfr[kt], acc[mt], 0, 0, 0);
                }
            }
        }

        // ---- C tile -> LDS (wave wv owns cols wv*16..+15) ----
        #pragma unroll
        for (int mt = 0; mt < 8; ++mt)
            #pragma unroll
            for (int r = 0; r < 4; ++r)
                Cs[mt * 16 + quad * 4 + r][wv * 16 + (lane & 15)] = acc[mt][r];
        __syncthreads();

        // ---- fused LSTM cell (8 units/thread) ----
        {
            short hn[8];
            #pragma unroll
            for (int i = 0; i < 8; ++i) {
                float4 gv = *(const float4*)&Cs[m][32 * q + 4 * i];
                float gi = xv[i].x + gv.x;
                float gf = xv[i].y + gv.y;
                float gg2 = xv[i].z + gv.z;
                float go = xv[i].w + gv.w;
                float iv = 1.f / (1.f + __expf(-gi));
                float fv = 1.f / (1.f + __expf(-gf));
                float tg = 1.f - 2.f / (__expf(2.f * gg2) + 1.f);
                float ov = 1.f / (1.f + __expf(-go));
                float cc = fmaf(fv, c8[i], iv * tg);
                c8[i] = cc;
                float th = 1.f - 2.f / (__expf(2.f * cc) + 1.f);
                hn[i] = f2bf(ov * th);
            }
            if (a0) {
                short4 h4 = {hn[0], hn[1], hn[2], hn[3]};
                *(short4*)&hout[hofs] = h4;
                *(short4*)&hc[((size_t)b * L_ + t) * 608 + u0] = h4;
            }
            if (a1) {
                short4 h4 = {hn[4], hn[5], hn[6], hn[7]};
                *(short4*)&hout[hofs + 4] = h4;
                *(short4*)&hc[((size_t)b * L_ + t) * 608 + u0 + 4] = h4;
            }
        }

        // ---- group barrier: 19 blocks (mb,*,d); padded per-group line ----
        if (s < L_ - 1) {
            // per-wave drain: all h stores have reached L2 before tid0 fences
            asm volatile("s_waitcnt vmcnt(0) lgkmcnt(0)" ::: "memory");
            __syncthreads();
            if (tid == 0) {
                __threadfence();   // release: wbl2 flushes block's stores to L3
                __hip_atomic_fetch_add(&syncv[g << 6], 1, __ATOMIC_RELEASE,
                                       __HIP_MEMORY_SCOPE_AGENT);
                const int tgt = 19 * (s + 1);
                while (__hip_atomic_load(&syncv[g << 6], __ATOMIC_ACQUIRE,
                                         __HIP_MEMORY_SCOPE_AGENT) < tgt)
                    __builtin_amdgcn_s_sleep(2);
                __threadfence();   // acquire: inv stale L1/L2 before next step
            }
            __syncthreads();       // also the intra-block barrier for Cs reuse
        }
    }
}

// ---------------------------------------------------------------------------
// k_step2 (fallback path): ONE recurrence step, both dirs.
// Grid (16 mb, 19 nb, 2 d), 256 thr. Identical arithmetic to k_rec2.
// ---------------------------------------------------------------------------
__global__ __launch_bounds__(256) void k_step2(const float* __restrict__ P1,
                                               const float* __restrict__ P2,
                                               const int* __restrict__ sem,
                                               const short* __restrict__ WFf,
                                               const short* __restrict__ WFb,
                                               short* __restrict__ hp,
                                               float* __restrict__ cbuf,
                                               short* __restrict__ hcat,
                                               int s)
{
    const int d  = blockIdx.z;
    const short* WF = d ? WFb : WFf;
    const int t = d ? (L_ - 1 - s) : s;
    const short* hin = hp + (size_t)(d * 2 + ((s + 1) & 1)) * HPSTR;
    short*      hout = hp + (size_t)(d * 2 + (s & 1)) * HPSTR;
    short* hc = hcat + (d ? 304 : 0);
    float* cp = cbuf + (size_t)d * (1024 * 304);

    const int m0 = blockIdx.x * 64;
    const int rt0 = blockIdx.x * 4;
    const int nb = blockIdx.y;
    const int tid  = threadIdx.x;
    const int lane = tid & 63;
    const int wv   = tid >> 6;
    const int quad = lane >> 4;

    __shared__ __align__(16) float Cs[64][68];

    f32x4 acc[4];
    #pragma unroll
    for (int mt = 0; mt < 4; ++mt) acc[mt] = (f32x4){0.f, 0.f, 0.f, 0.f};

    if (s > 0) {
        const short* wp = WF + ((size_t)(nb * 4 + wv) * 10) * 512 + lane * 8;
        #pragma unroll
        for (int kt = 0; kt < 10; ++kt) {
            bf16x8 bf = *(const bf16x8*)(wp + kt * 512);
            #pragma unroll
            for (int mt = 0; mt < 4; ++mt) {
                bf16x8 af = *(const bf16x8*)&hin[((size_t)(rt0 + mt) * 10 + kt) * 512 + lane * 8];
                acc[mt] = __builtin_amdgcn_mfma_f32_16x16x32_bf16(af, bf, acc[mt], 0, 0, 0);
            }
        }
    }

    #pragma unroll
    for (int mt = 0; mt < 4; ++mt)
        #pragma unroll
        for (int r = 0; r < 4; ++r)
            Cs[mt * 16 + quad * 4 + r][wv * 16 + (lane & 15)] = acc[mt][r];
    __syncthreads();

    const int m = tid >> 2;
    const int q = tid & 3;
    const int b = m0 + m;
    const int u0 = nb * 16 + 4 * q;
    if (u0 < H_) {
        const int svt = sem[b * L_ + t];
        const size_t pcol = (size_t)d * 1216 + 4 * u0;
        const float* p2r = P2 + (size_t)svt * PSTR + pcol;
        const float* p1r = P1 + (size_t)b * PSTR + pcol;
        float4 xv[4];
        #pragma unroll
        for (int i = 0; i < 4; ++i) xv[i] = *(const float4*)&p2r[4 * i];
        if (svt != 0) {
            #pragma unroll
            for (int i = 0; i < 4; ++i) {
                float4 a = *(const float4*)&p1r[4 * i];
                xv[i].x += a.x; xv[i].y += a.y; xv[i].z += a.z; xv[i].w += a.w;
            }
        }
        float4 cpv = (s > 0) ? *(const float4*)&cp[(size_t)b * 304 + u0]
                             : make_float4(0.f, 0.f, 0.f, 0.f);
        float cold[4] = {cpv.x, cpv.y, cpv.z, cpv.w};
        float cnew[4];
        short hn[4];
        #pragma unroll
        for (int i = 0; i < 4; ++i) {
            float4 gv = *(const float4*)&Cs[m][16 * q + 4 * i];
            float gi = xv[i].x + gv.x;
            float gf = xv[i].y + gv.y;
            float gg = xv[i].z + gv.z;
            float go = xv[i].w + gv.w;
            float iv = 1.f / (1.f + __expf(-gi));
            float fv = 1.f / (1.f + __expf(-gf));
            float tg = 1.f - 2.f / (__expf(2.f * gg) + 1.f);
            float ov = 1.f / (1.f + __expf(-go));
            float cc = fmaf(fv, cold[i], iv * tg);
            cnew[i] = cc;
            float th = 1.f - 2.f / (__expf(2.f * cc) + 1.f);
            hn[i] = f2bf(ov * th);
        }
        *(float4*)&cp[(size_t)b * 304 + u0] = make_float4(cnew[0], cnew[1], cnew[2], cnew[3]);
        short4 h4 = {hn[0], hn[1], hn[2], hn[3]};
        {
            int rt = b >> 4, ktu = u0 >> 5;
            int fl = (b & 15) | (((u0 >> 3) & 3) << 4);
            *(short4*)&hout[((size_t)(rt * 10 + ktu) * 512) + (size_t)fl * 8 + (u0 & 7)] = h4;
        }
        *(short4*)&hc[((size_t)b * L_ + t) * 608 + u0] = h4;
    }
}

// ---------------------------------------------------------------------------
// k_out: V = relu(hcat @ WAT^T + ba)  bf16 MFMA.  M=18432, N=304(300), K=608.
// ---------------------------------------------------------------------------
__global__ __launch_bounds__(256) void k_out(const short* __restrict__ hcat,
                                             const short* __restrict__ WAT,
                                             const float* __restrict__ ba,
                                             float* __restrict__ out)
{
    const int m0 = blockIdx.x * 64;
    const int tid = threadIdx.x;
    const int lane = tid & 63;
    const int wv = tid >> 6;
    const int lm = lane & 15;
    const int quad = lane >> 4;

    __shared__ __align__(16) short A_s[64][616];

    for (int idx = tid; idx < 4864; idx += 256) {   // 64 rows * 76 chunks
        int r = idx / 76, c8 = idx - r * 76;
        *(int4*)&A_s[r][c8 * 8] = *(const int4*)&hcat[(size_t)(m0 + r) * 608 + c8 * 8];
    }
    __syncthreads();

    f32x4 acc[4][5];
    #pragma unroll
    for (int mt = 0; mt < 4; ++mt)
        #pragma unroll
        for (int q = 0; q < 5; ++q)
            acc[mt][q] = (f32x4){0.f, 0.f, 0.f, 0.f};

    for (int kt = 0; kt < 19; ++kt) {
        bf16x8 af[4];
        #pragma unroll
        for (int mt = 0; mt < 4; ++mt)
            af[mt] = *(const bf16x8*)&A_s[mt * 16 + lm][kt * 32 + quad * 8];
        #pragma unroll
        for (int q = 0; q < 5; ++q) {
            int nt = wv + 4 * q;
            if (nt < 19) {
                bf16x8 bf = *(const bf16x8*)&WAT[((size_t)(nt * 19 + kt) * 64 + lane) * 8];
                #pragma unroll
                for (int mt = 0; mt < 4; ++mt)
                    acc[mt][q] = __builtin_amdgcn_mfma_f32_16x16x32_bf16(
                        af[mt], bf, acc[mt][q], 0, 0, 0);
            }
        }
    }

    #pragma unroll
    for (int q = 0; q < 5; ++q) {
        int nt = wv + 4 * q;
        if (nt < 19) {
            int o = nt * 16 + lm;
            if (o < H_) {
                float bias = ba[o];
                #pragma unroll
                for (int mt = 0; mt < 4; ++mt) {
                    #pragma unroll
                    for (int r = 0; r < 4; ++r) {
                        int m = m0 + mt * 16 + quad * 4 + r;
                        float v = acc[mt][q][r] + bias;
                        out[(size_t)m * H_ + o] = v > 0.f ? v : 0.f;
                    }
                }
            }
        }
    }
}

// ---------------------------------------------------------------------------
extern "C" void kernel_launch(void* const* d_in, const int* in_sizes, int n_in,
                              void* d_out, int out_size, void* d_ws, size_t ws_size,
                              hipStream_t stream) {
    const int*   word       = (const int*)  d_in[0];
    const int*   sem        = (const int*)  d_in[1];
    const float* word_table = (const float*)d_in[2];
    const float* sem_table  = (const float*)d_in[3];
    const float* Wih_f      = (const float*)d_in[4];
    const float* Whh_f      = (const float*)d_in[5];
    const float* bih_f      = (const float*)d_in[6];
    const float* bhh_f      = (const float*)d_in[7];
    const float* Wih_b      = (const float*)d_in[8];
    const float* Whh_b      = (const float*)d_in[9];
    const float* bih_b      = (const float*)d_in[10];
    const float* bhh_b      = (const float*)d_in[11];
    const float* Wa         = (const float*)d_in[12];
    const float* ba         = (const float*)d_in[13];
    const float* Wb         = (const float*)d_in[14];
    const float* bbv        = (const float*)d_in[15];

    float* out = (float*)d_out;
    float* ws  = (float*)d_ws;

    float* P1    = ws + OFF_P1;
    float* P2    = ws + OFF_P2;
    short* hcat  = (short*)(ws + OFF_HCAT);
    float* ag    = ws + OFF_AG;
    float* WbT   = ws + OFF_WBT;
    short* WFf   = (short*)(ws + OFF_WFF);
    short* WFb   = (short*)(ws + OFF_WFB);
    short* WAT   = (short*)(ws + OFF_WAT);
    short* WcatP = (short*)(ws + OFF_WCP);
    short* hp    = (short*)(ws + OFF_HP);
    float* cbuf  = ws + OFF_C;
    int*   syncv = (int*)(ws + OFF_SYNC);

    // weight re-layouts (every call; inputs restored each launch)
    k_prep<<<dim3(352), dim3(256), 0, stream>>>(Wb, WbT, syncv);
    k_prep_wcp<<<dim3((2 * NPAD * 320 + 255) / 256), dim3(256), 0, stream>>>(
        Wih_f, Wih_b, WcatP);
    k_prep_whh<<<dim3(1520, 2), dim3(256), 0, stream>>>(Whh_f, Whh_b, WFf, WFb);
    k_prep_wa<<<dim3(722), dim3(256), 0, stream>>>(Wa, WAT);

    // v_g branch
    k_ag<<<dim3(B_), dim3(256), 0, stream>>>(sem, sem_table, ag);
    k_vg<<<dim3(B_ / 16), dim3(256), 0, stream>>>(ag, WbT, bbv, out);

    // factored input GEMMs: P1 (word part) + P2' (sememe part + bias)
    k_p<<<dim3(26, 19), dim3(256), 0, stream>>>(
        word, word_table, sem_table, WcatP,
        bih_f, bhh_f, bih_b, bhh_b, P1, P2);

    // recurrence: cooperative single-launch (co-residency guaranteed) with
    // padded per-group barriers; proven 18-launch fallback else.
    int useCoop = 0;
    {
        int dev = 0, coopAttr = 0, numCU = 0, maxBlk = 0;
        (void)hipGetDevice(&dev);
        (void)hipDeviceGetAttribute(&coopAttr, hipDeviceAttributeCooperativeLaunch, dev);
        (void)hipDeviceGetAttribute(&numCU, hipDeviceAttributeMultiprocessorCount, dev);
        (void)hipOccupancyMaxActiveBlocksPerMultiprocessor(&maxBlk, k_rec2, 256, 0);
        if (coopAttr && (long)maxBlk * (long)numCU >= 304) useCoop = 1;
    }
    if (useCoop) {
        void* args[] = {(void*)&P1, (void*)&P2, (void*)&sem,
                        (void*)&WFf, (void*)&WFb, (void*)&hp, (void*)&hcat,
                        (void*)&syncv};
        hipError_t e = hipLaunchCooperativeKernel((const void*)k_rec2,
                                                  dim3(8, 19, 2), dim3(256),
                                                  args, 0, stream);
        if (e != hipSuccess) useCoop = 0;
    }
    if (!useCoop) {
        for (int s = 0; s < L_; ++s) {
            k_step2<<<dim3(16, 19, 2), dim3(256), 0, stream>>>(
                P1, P2, sem, WFf, WFb, hp, cbuf, hcat, s);
        }
    }

    // output projection (bf16 MFMA)
    k_out<<<dim3(M_ / 64), dim3(256), 0, stream>>>(hcat, WAT, ba, out);
}